// Round 6
// baseline (654.005 us; speedup 1.0000x reference)
//
#include <hip/hip_runtime.h>

typedef unsigned short ushort_t;
typedef unsigned int uint_t;

#define L_TOK 3072
#define DMODEL 512
#define WELEM 262144   // 512*512

using bf16x8 = __attribute__((ext_vector_type(8))) short;
using f32x4  = __attribute__((ext_vector_type(4))) float;

__device__ __forceinline__ float b2f(ushort_t u) {
    union { uint_t i; float f; } c; c.i = ((uint_t)u) << 16; return c.f;
}
__device__ __forceinline__ ushort_t f2b(float f) {
    union { float f; uint_t i; } c; c.f = f;
    uint_t x = c.i;
    return (ushort_t)((x + 0x7fffu + ((x >> 16) & 1u)) >> 16);  // RNE
}

// ---------------- Weight convert: 6 matrices of 512x512 fp32 -> bf16 (RNE)
__global__ __launch_bounds__(256) void convert_weights(
    const float* __restrict__ Wq, const float* __restrict__ Wk, const float* __restrict__ Wv,
    const float* __restrict__ Wo, const float* __restrict__ W1, const float* __restrict__ W2,
    ushort_t* __restrict__ WB)
{
    int gid = blockIdx.x * 256 + threadIdx.x;     // 393216 threads, 4 floats each
    int mat = gid >> 16;
    int off = (gid & 65535) * 4;
    const float* src;
    switch (mat) {
        case 0: src = Wq; break;
        case 1: src = Wk; break;
        case 2: src = Wv; break;
        case 3: src = Wo; break;
        case 4: src = W1; break;
        default: src = W2; break;
    }
    float4 v = *reinterpret_cast<const float4*>(src + off);
    uint2 o;
    o.x = (uint_t)f2b(v.x) | ((uint_t)f2b(v.y) << 16);
    o.y = (uint_t)f2b(v.z) | ((uint_t)f2b(v.w) << 16);
    *reinterpret_cast<uint2*>(&WB[mat * WELEM + off]) = o;
}

// ---------------- Embedding (fp32 tables -> bf16 X)
__global__ __launch_bounds__(256) void embed_kernel(
    const int* __restrict__ idx,
    const float* __restrict__ Wt, const float* __restrict__ bt,
    const float* __restrict__ Wa, const float* __restrict__ ba,
    const float* __restrict__ Wm, const float* __restrict__ bm,
    const float* __restrict__ sos, ushort_t* __restrict__ X)
{
    int gid = blockIdx.x * 256 + threadIdx.x;   // 3072*512 total
    int tok = gid >> 9;
    int d = gid & 511;
    float val;
    if (tok == 0) {
        val = sos[d];
    } else {
        int id = idx[tok - 1];
        int t = id / 219;            // 73*3
        int a = (id / 3) % 73;
        int m = id % 3;
        val = Wt[d * 15 + t] + bt[d]
            + Wa[d * 73 + a] + ba[d]
            + Wm[d * 3 + m] + bm[d];
    }
    X[gid] = f2b(val);
}

// ---------------- start[] scan (ping-pong, race-free)
__global__ __launch_bounds__(1024) void scan_start(const int* __restrict__ seq, int* __restrict__ start)
{
    __shared__ int buf0[1024];
    __shared__ int buf1[1024];
    int tid = threadIdx.x;
    int carry = 0;
    for (int c = 0; c < 3; c++) {
        int i = c * 1024 + tid;
        int b;
        if (i <= 1) b = i;
        else b = (seq[i - 1] == 0) ? i : 0;
        buf0[tid] = b;
        __syncthreads();
        int* src = buf0;
        int* dst = buf1;
        for (int off = 1; off < 1024; off <<= 1) {
            int v = src[tid];
            if (tid >= off) { int u = src[tid - off]; if (u > v) v = u; }
            dst[tid] = v;
            __syncthreads();
            int* t = src; src = dst; dst = t;
        }
        int val = src[tid] > carry ? src[tid] : carry;
        start[i] = val;
        int tot = src[1023] > carry ? src[1023] : carry;
        __syncthreads();
        carry = tot;
    }
}

// ---------------- GEMM: C[3072,512] = A@W^T + bias; register-A, no LDS, no barriers.
// Each wave: preload its 16-row A slice across full K=512 (64 VGPRs, MFMA A-layout),
// stream B fragments straight from global (weights are L2/L1-resident), 64 MFMAs.
template<int RELU>
__global__ __launch_bounds__(256) void gemm512(
    const ushort_t* __restrict__ A,
    const ushort_t* __restrict__ Wp0, const ushort_t* __restrict__ Wp1, const ushort_t* __restrict__ Wp2,
    const float* __restrict__ bp0, const float* __restrict__ bp1, const float* __restrict__ bp2,
    ushort_t* __restrict__ Cp0, ushort_t* __restrict__ Cp1, ushort_t* __restrict__ Cp2)
{
    const ushort_t* W = Wp0; const float* bias = bp0; ushort_t* C = Cp0;
    if (blockIdx.z == 1) { W = Wp1; bias = bp1; C = Cp1; }
    else if (blockIdx.z == 2) { W = Wp2; bias = bp2; C = Cp2; }

    const int lane = threadIdx.x & 63;
    const int w = threadIdx.x >> 6;      // wave -> m sub-tile
    const int lm = lane & 15;
    const int q4 = lane >> 4;

    const int m0 = blockIdx.x * 64;
    const int n0 = blockIdx.y * 64;

    // Preload A fragments: lane holds A[m0+w*16+lm][kk*32 + q4*8 .. +8] for kk=0..15
    const ushort_t* abase = A + (size_t)(m0 + w * 16 + lm) * 512 + q4 * 8;
    bf16x8 af[16];
#pragma unroll
    for (int kk = 0; kk < 16; kk++)
        af[kk] = *reinterpret_cast<const bf16x8*>(abase + kk * 32);

    f32x4 acc[4];
#pragma unroll
    for (int i = 0; i < 4; i++) acc[i] = (f32x4){0.f, 0.f, 0.f, 0.f};

    // B fragments: lane holds W[n0+nt*16+lm][kk*32 + q4*8 .. +8]
    const ushort_t* bbase = W + (size_t)(n0 + lm) * 512 + q4 * 8;
#pragma unroll 4
    for (int kk = 0; kk < 16; kk++) {
        bf16x8 bf0 = *reinterpret_cast<const bf16x8*>(bbase + kk * 32);
        bf16x8 bf1 = *reinterpret_cast<const bf16x8*>(bbase + 16 * 512 + kk * 32);
        bf16x8 bf2 = *reinterpret_cast<const bf16x8*>(bbase + 32 * 512 + kk * 32);
        bf16x8 bf3 = *reinterpret_cast<const bf16x8*>(bbase + 48 * 512 + kk * 32);
        acc[0] = __builtin_amdgcn_mfma_f32_16x16x32_bf16(af[kk], bf0, acc[0], 0, 0, 0);
        acc[1] = __builtin_amdgcn_mfma_f32_16x16x32_bf16(af[kk], bf1, acc[1], 0, 0, 0);
        acc[2] = __builtin_amdgcn_mfma_f32_16x16x32_bf16(af[kk], bf2, acc[2], 0, 0, 0);
        acc[3] = __builtin_amdgcn_mfma_f32_16x16x32_bf16(af[kk], bf3, acc[3], 0, 0, 0);
    }

#pragma unroll
    for (int nt = 0; nt < 4; nt++) {
        int col = n0 + nt * 16 + lm;
        float bv = bias[col];
#pragma unroll
        for (int r = 0; r < 4; r++) {
            int row = m0 + w * 16 + q4 * 4 + r;
            float v = acc[nt][r] + bv;
            if (RELU) v = (v > 0.f) ? v : 0.01f * v;
            C[(size_t)row * 512 + col] = f2b(v);
        }
    }
}

// ---------------- Sparse attention: keys = {0} ∪ [start[i], i-1], one wave per (token i, head h)
// 4-way split accumulators (QK and PV) break the dependent-FMA chains;
// next-chunk K/V prefetch hides global latency for multi-chunk (tail) waves.
__global__ __launch_bounds__(256) void attn_kernel(
    const ushort_t* __restrict__ Q, const ushort_t* __restrict__ K,
    const ushort_t* __restrict__ V, const int* __restrict__ START,
    ushort_t* __restrict__ O)
{
    __shared__ ushort_t Vs[4][64 * 66];   // stride 66: conflict-free writes (measured 0 conflicts)
    __shared__ float ps[4][64];

    int w = threadIdx.x >> 6;
    int lane = threadIdx.x & 63;
    int wid = blockIdx.x * 4 + w;
    int i = wid >> 3;
    int h = wid & 7;

    float qv = b2f(Q[(size_t)i * 512 + h * 64 + lane]) * 0.125f;  // fold 1/sqrt(64)
    int si = START[i];
    if (si < 1) si = 1;
    if (si > i) si = i;
    int nk = (i == 0) ? 1 : (i - si + 1);

    // Load chunk 0 K/V rows (lane-per-key)
    uint4 kr[8], vr[8];
    {
        int t = lane;
        int j = (t == 0) ? 0 : (si + t - 1);
        if (t >= nk) j = 0;
        if (j > L_TOK - 1) j = L_TOK - 1;
        const uint4* kp = reinterpret_cast<const uint4*>(&K[(size_t)j * 512 + h * 64]);
        const uint4* vp = reinterpret_cast<const uint4*>(&V[(size_t)j * 512 + h * 64]);
#pragma unroll
        for (int c = 0; c < 8; c++) kr[c] = kp[c];
#pragma unroll
        for (int c = 0; c < 8; c++) vr[c] = vp[c];
    }

    float m_run = -INFINITY, l_run = 0.f;
    float oa0 = 0.f, oa1 = 0.f, oa2 = 0.f, oa3 = 0.f;

    for (int t0 = 0; t0 < nk; t0 += 64) {
        bool valid = (t0 + lane) < nk;

        // Stash V row to LDS (vr dead after this)
#pragma unroll
        for (int c = 0; c < 8; c++)
            *reinterpret_cast<uint4*>(&Vs[w][lane * 66 + c * 8]) = vr[c];

        // QK dot: 4 independent accumulators (chains of 16 FMAs each)
        float sa0 = 0.f, sa1 = 0.f, sa2 = 0.f, sa3 = 0.f;
#pragma unroll
        for (int c = 0; c < 8; c++) {
            uint_t uu[4] = {kr[c].x, kr[c].y, kr[c].z, kr[c].w};
            float part = 0.f;
#pragma unroll
            for (int p2 = 0; p2 < 4; p2++) {
                int d = c * 8 + p2 * 2;
                part += __shfl(qv, d) * b2f((ushort_t)(uu[p2] & 0xffffu));
                part += __shfl(qv, d + 1) * b2f((ushort_t)(uu[p2] >> 16));
            }
            if ((c & 3) == 0) sa0 += part;
            else if ((c & 3) == 1) sa1 += part;
            else if ((c & 3) == 2) sa2 += part;
            else sa3 += part;
        }
        float s = (sa0 + sa1) + (sa2 + sa3);
        if (!valid) s = -INFINITY;

        // Prefetch next chunk's K/V (kr/vr now dead) — overlaps softmax + PV
        if (t0 + 64 < nk) {
            int tn = t0 + 64 + lane;        // >= 64, never the key-0 slot
            int jn = si + tn - 1;
            if (tn >= nk) jn = 0;
            if (jn > L_TOK - 1) jn = L_TOK - 1;
            const uint4* kp2 = reinterpret_cast<const uint4*>(&K[(size_t)jn * 512 + h * 64]);
            const uint4* vp2 = reinterpret_cast<const uint4*>(&V[(size_t)jn * 512 + h * 64]);
#pragma unroll
            for (int c = 0; c < 8; c++) kr[c] = kp2[c];
#pragma unroll
            for (int c = 0; c < 8; c++) vr[c] = vp2[c];
        }

        // Online softmax
        float tmax = s;
#pragma unroll
        for (int off = 32; off > 0; off >>= 1) tmax = fmaxf(tmax, __shfl_xor(tmax, off));
        float m_new = fmaxf(m_run, tmax);
        float p = valid ? __expf(s - m_new) : 0.f;
        float psum = p;
#pragma unroll
        for (int off = 32; off > 0; off >>= 1) psum += __shfl_xor(psum, off);
        float alpha = (m_run == -INFINITY) ? 0.f : __expf(m_run - m_new);
        l_run = l_run * alpha + psum;
        oa0 *= alpha; oa1 *= alpha; oa2 *= alpha; oa3 *= alpha;

        ps[w][lane] = p;    // invalid lanes hold 0

        // PV: 4 independent accumulators (chains of 16 FMAs each)
#pragma unroll
        for (int j2 = 0; j2 < 64; j2 += 4) {
            oa0 += ps[w][j2 + 0] * b2f(Vs[w][(j2 + 0) * 66 + lane]);
            oa1 += ps[w][j2 + 1] * b2f(Vs[w][(j2 + 1) * 66 + lane]);
            oa2 += ps[w][j2 + 2] * b2f(Vs[w][(j2 + 2) * 66 + lane]);
            oa3 += ps[w][j2 + 3] * b2f(Vs[w][(j2 + 3) * 66 + lane]);
        }
        m_run = m_new;
    }
    float o_acc = (oa0 + oa1) + (oa2 + oa3);
    float inv = (l_run > 0.f) ? (1.f / l_run) : 0.f;
    O[(size_t)i * 512 + h * 64 + lane] = f2b(o_acc * inv);
}

// ---------------- LayerNorm (one wave per token); RESID adds R; F32OUT selects output format
template<int RESID, int F32OUT>
__global__ __launch_bounds__(256) void ln_kernel(
    const ushort_t* __restrict__ X, const ushort_t* __restrict__ R,
    const float* __restrict__ g, const float* __restrict__ be,
    void* __restrict__ outv)
{
    int tok = blockIdx.x * 4 + (threadIdx.x >> 6);
    int lane = threadIdx.x & 63;
    size_t base = (size_t)tok * 512 + lane * 8;

    float v[8];
    {
        uint4 ux = *reinterpret_cast<const uint4*>(&X[base]);
        uint_t ua[4] = {ux.x, ux.y, ux.z, ux.w};
#pragma unroll
        for (int p = 0; p < 4; p++) {
            v[2 * p] = b2f((ushort_t)(ua[p] & 0xffffu));
            v[2 * p + 1] = b2f((ushort_t)(ua[p] >> 16));
        }
        if (RESID) {
            uint4 ur = *reinterpret_cast<const uint4*>(&R[base]);
            uint_t ub[4] = {ur.x, ur.y, ur.z, ur.w};
#pragma unroll
            for (int p = 0; p < 4; p++) {
                v[2 * p] += b2f((ushort_t)(ub[p] & 0xffffu));
                v[2 * p + 1] += b2f((ushort_t)(ub[p] >> 16));
            }
        }
    }
    float sum = 0.f;
#pragma unroll
    for (int j = 0; j < 8; j++) sum += v[j];
#pragma unroll
    for (int off = 32; off > 0; off >>= 1) sum += __shfl_xor(sum, off);
    float mu = sum * (1.f / 512.f);
    float var = 0.f;
#pragma unroll
    for (int j = 0; j < 8; j++) { float d = v[j] - mu; var += d * d; }
#pragma unroll
    for (int off = 32; off > 0; off >>= 1) var += __shfl_xor(var, off);
    float rstd = rsqrtf(var * (1.f / 512.f) + 1e-5f);

    const float4* gp = reinterpret_cast<const float4*>(g);
    const float4* bp = reinterpret_cast<const float4*>(be);
    float4 g0 = gp[2 * lane], g1 = gp[2 * lane + 1];
    float4 b0 = bp[2 * lane], b1 = bp[2 * lane + 1];
    float gg[8] = {g0.x, g0.y, g0.z, g0.w, g1.x, g1.y, g1.z, g1.w};
    float bb[8] = {b0.x, b0.y, b0.z, b0.w, b1.x, b1.y, b1.z, b1.w};

    float o[8];
#pragma unroll
    for (int j = 0; j < 8; j++) o[j] = (v[j] - mu) * rstd * gg[j] + bb[j];

    if (F32OUT) {
        float* outf = (float*)outv;
        float4 o0 = {o[0], o[1], o[2], o[3]};
        float4 o1 = {o[4], o[5], o[6], o[7]};
        *reinterpret_cast<float4*>(&outf[base]) = o0;
        *reinterpret_cast<float4*>(&outf[base + 4]) = o1;
    } else {
        ushort_t* outb = (ushort_t*)outv;
        uint_t outp[4];
#pragma unroll
        for (int p = 0; p < 4; p++)
            outp[p] = (uint_t)f2b(o[2 * p]) | ((uint_t)f2b(o[2 * p + 1]) << 16);
        uint4 ov; ov.x = outp[0]; ov.y = outp[1]; ov.z = outp[2]; ov.w = outp[3];
        *reinterpret_cast<uint4*>(&outb[base]) = ov;
    }
}

extern "C" void kernel_launch(void* const* d_in, const int* in_sizes, int n_in,
                              void* d_out, int out_size, void* d_ws, size_t ws_size,
                              hipStream_t stream) {
    const int*   idx = (const int*)d_in[0];
    const int*   seq = (const int*)d_in[1];
    const float* Wt  = (const float*)d_in[2];
    const float* bt  = (const float*)d_in[3];
    const float* Wa  = (const float*)d_in[4];
    const float* ba  = (const float*)d_in[5];
    const float* Wm  = (const float*)d_in[6];
    const float* bm  = (const float*)d_in[7];
    const float* sos = (const float*)d_in[8];
    const float* Wq  = (const float*)d_in[9];
    const float* bq  = (const float*)d_in[10];
    const float* Wk  = (const float*)d_in[11];
    const float* bk  = (const float*)d_in[12];
    const float* Wv  = (const float*)d_in[13];
    const float* bv  = (const float*)d_in[14];
    const float* Wo  = (const float*)d_in[15];
    const float* bo  = (const float*)d_in[16];
    const float* W1  = (const float*)d_in[17];
    const float* b1  = (const float*)d_in[18];
    const float* W2  = (const float*)d_in[19];
    const float* b2  = (const float*)d_in[20];
    const float* g1  = (const float*)d_in[21];
    const float* be1 = (const float*)d_in[22];
    const float* g2  = (const float*)d_in[23];
    const float* be2 = (const float*)d_in[24];

    const size_t NB = (size_t)L_TOK * DMODEL;

    int* START = (int*)d_ws;
    ushort_t* WB = (ushort_t*)d_ws + 16384;
    ushort_t* WQc = WB + 0 * WELEM;
    ushort_t* WKc = WB + 1 * WELEM;
    ushort_t* WVc = WB + 2 * WELEM;
    ushort_t* WOc = WB + 3 * WELEM;
    ushort_t* W1c = WB + 4 * WELEM;
    ushort_t* W2c = WB + 5 * WELEM;
    ushort_t* bufs = WB + 6 * WELEM;
    ushort_t* B0 = bufs;            // X / attn-out / next-layer X
    ushort_t* B1 = bufs + 1 * NB;   // Q / O-proj out / FF hidden
    ushort_t* B2 = bufs + 2 * NB;   // K / XA
    ushort_t* B3 = bufs + 3 * NB;   // V / FF2 out

    convert_weights<<<1536, 256, 0, stream>>>(Wq, Wk, Wv, Wo, W1, W2, WB);
    embed_kernel<<<6144, 256, 0, stream>>>(idx, Wt, bt, Wa, ba, Wm, bm, sos, B0);
    scan_start<<<1, 1024, 0, stream>>>(seq, START);

    for (int layer = 0; layer < 2; layer++) {
        gemm512<0><<<dim3(48, 8, 3), 256, 0, stream>>>(B0, WQc, WKc, WVc, bq, bk, bv, B1, B2, B3);
        attn_kernel<<<6144, 256, 0, stream>>>(B1, B2, B3, START, B0);
        gemm512<0><<<dim3(48, 8, 1), 256, 0, stream>>>(B0, WOc, WOc, WOc, bo, bo, bo, B1, B1, B1);
        ln_kernel<0, 0><<<768, 256, 0, stream>>>(B1, B1, g1, be1, B2);          // XA -> B2
        gemm512<1><<<dim3(48, 8, 1), 256, 0, stream>>>(B2, W1c, W1c, W1c, b1, b1, b1, B1, B1, B1);
        gemm512<0><<<dim3(48, 8, 1), 256, 0, stream>>>(B1, W2c, W2c, W2c, b2, b2, b2, B3, B3, B3);
        if (layer == 0)
            ln_kernel<1, 0><<<768, 256, 0, stream>>>(B3, B2, g2, be2, B0);      // bf16 internal
        else
            ln_kernel<1, 1><<<768, 256, 0, stream>>>(B3, B2, g2, be2, d_out);   // fp32 final output
    }
}

// Round 7
// 394.720 us; speedup vs baseline: 1.6569x; 1.6569x over previous
//
#include <hip/hip_runtime.h>

typedef unsigned short ushort_t;
typedef unsigned int uint_t;

#define L_TOK 3072
#define DMODEL 512
#define WELEM 262144   // 512*512

using bf16x8 = __attribute__((ext_vector_type(8))) short;
using f32x4  = __attribute__((ext_vector_type(4))) float;

__device__ __forceinline__ float b2f(ushort_t u) {
    union { uint_t i; float f; } c; c.i = ((uint_t)u) << 16; return c.f;
}
__device__ __forceinline__ ushort_t f2b(float f) {
    union { float f; uint_t i; } c; c.f = f;
    uint_t x = c.i;
    return (ushort_t)((x + 0x7fffu + ((x >> 16) & 1u)) >> 16);  // RNE
}

// ---------------- Weight convert: 6 matrices of 512x512 fp32 -> bf16 (RNE)
__global__ __launch_bounds__(256) void convert_weights(
    const float* __restrict__ Wq, const float* __restrict__ Wk, const float* __restrict__ Wv,
    const float* __restrict__ Wo, const float* __restrict__ W1, const float* __restrict__ W2,
    ushort_t* __restrict__ WB)
{
    int gid = blockIdx.x * 256 + threadIdx.x;     // 393216 threads, 4 floats each
    int mat = gid >> 16;
    int off = (gid & 65535) * 4;
    const float* src;
    switch (mat) {
        case 0: src = Wq; break;
        case 1: src = Wk; break;
        case 2: src = Wv; break;
        case 3: src = Wo; break;
        case 4: src = W1; break;
        default: src = W2; break;
    }
    float4 v = *reinterpret_cast<const float4*>(src + off);
    uint2 o;
    o.x = (uint_t)f2b(v.x) | ((uint_t)f2b(v.y) << 16);
    o.y = (uint_t)f2b(v.z) | ((uint_t)f2b(v.w) << 16);
    *reinterpret_cast<uint2*>(&WB[mat * WELEM + off]) = o;
}

// ---------------- Embedding (fp32 tables -> bf16 X)
__global__ __launch_bounds__(256) void embed_kernel(
    const int* __restrict__ idx,
    const float* __restrict__ Wt, const float* __restrict__ bt,
    const float* __restrict__ Wa, const float* __restrict__ ba,
    const float* __restrict__ Wm, const float* __restrict__ bm,
    const float* __restrict__ sos, ushort_t* __restrict__ X)
{
    int gid = blockIdx.x * 256 + threadIdx.x;   // 3072*512 total
    int tok = gid >> 9;
    int d = gid & 511;
    float val;
    if (tok == 0) {
        val = sos[d];
    } else {
        int id = idx[tok - 1];
        int t = id / 219;            // 73*3
        int a = (id / 3) % 73;
        int m = id % 3;
        val = Wt[d * 15 + t] + bt[d]
            + Wa[d * 73 + a] + ba[d]
            + Wm[d * 3 + m] + bm[d];
    }
    X[gid] = f2b(val);
}

// ---------------- start[] scan (ping-pong, race-free)
__global__ __launch_bounds__(1024) void scan_start(const int* __restrict__ seq, int* __restrict__ start)
{
    __shared__ int buf0[1024];
    __shared__ int buf1[1024];
    int tid = threadIdx.x;
    int carry = 0;
    for (int c = 0; c < 3; c++) {
        int i = c * 1024 + tid;
        int b;
        if (i <= 1) b = i;
        else b = (seq[i - 1] == 0) ? i : 0;
        buf0[tid] = b;
        __syncthreads();
        int* src = buf0;
        int* dst = buf1;
        for (int off = 1; off < 1024; off <<= 1) {
            int v = src[tid];
            if (tid >= off) { int u = src[tid - off]; if (u > v) v = u; }
            dst[tid] = v;
            __syncthreads();
            int* t = src; src = dst; dst = t;
        }
        int val = src[tid] > carry ? src[tid] : carry;
        start[i] = val;
        int tot = src[1023] > carry ? src[1023] : carry;
        __syncthreads();
        carry = tot;
    }
}

// ---------------- GEMM: C[3072,512] = A@W^T + bias; A,W,C bf16, bias fp32, fp32 acc
// (reverted to the round-4/5 LDS-staged version — known good; the register-A
//  variant spilled af[] to scratch via runtime-indexed array and was 10x slower)
template<int RELU>
__global__ __launch_bounds__(256) void gemm512(
    const ushort_t* __restrict__ A,
    const ushort_t* __restrict__ Wp0, const ushort_t* __restrict__ Wp1, const ushort_t* __restrict__ Wp2,
    const float* __restrict__ bp0, const float* __restrict__ bp1, const float* __restrict__ bp2,
    ushort_t* __restrict__ Cp0, ushort_t* __restrict__ Cp1, ushort_t* __restrict__ Cp2)
{
    const ushort_t* W = Wp0; const float* bias = bp0; ushort_t* C = Cp0;
    if (blockIdx.z == 1) { W = Wp1; bias = bp1; C = Cp1; }
    else if (blockIdx.z == 2) { W = Wp2; bias = bp2; C = Cp2; }

    __shared__ ushort_t As[64 * 72];
    __shared__ ushort_t Bs[64 * 72];

    const int tid = threadIdx.x;
    const int lane = tid & 63;
    const int w = tid >> 6;
    const int lm = lane & 15;
    const int q4 = lane >> 4;

    const int m0 = blockIdx.x * 64;
    const int n0 = blockIdx.y * 64;

    f32x4 acc[4];
#pragma unroll
    for (int i = 0; i < 4; i++) acc[i] = (f32x4){0.f, 0.f, 0.f, 0.f};

    for (int k0 = 0; k0 < 512; k0 += 64) {
        for (int c = tid; c < 512; c += 256) {
            int row = c >> 3, col = (c & 7) << 3;
            uint4 va = *reinterpret_cast<const uint4*>(&A[(size_t)(m0 + row) * 512 + k0 + col]);
            *reinterpret_cast<uint4*>(&As[row * 72 + col]) = va;
            uint4 vb = *reinterpret_cast<const uint4*>(&W[(size_t)(n0 + row) * 512 + k0 + col]);
            *reinterpret_cast<uint4*>(&Bs[row * 72 + col]) = vb;
        }
        __syncthreads();
#pragma unroll
        for (int kk = 0; kk < 64; kk += 32) {
            bf16x8 af = *reinterpret_cast<const bf16x8*>(&As[(w * 16 + lm) * 72 + kk + q4 * 8]);
#pragma unroll
            for (int nt = 0; nt < 4; nt++) {
                bf16x8 bf = *reinterpret_cast<const bf16x8*>(&Bs[(nt * 16 + lm) * 72 + kk + q4 * 8]);
                acc[nt] = __builtin_amdgcn_mfma_f32_16x16x32_bf16(af, bf, acc[nt], 0, 0, 0);
            }
        }
        __syncthreads();
    }

#pragma unroll
    for (int nt = 0; nt < 4; nt++) {
        int col = n0 + nt * 16 + lm;
        float bv = bias[col];
#pragma unroll
        for (int r = 0; r < 4; r++) {
            int row = m0 + w * 16 + q4 * 4 + r;
            float v = acc[nt][r] + bv;
            if (RELU) v = (v > 0.f) ? v : 0.01f * v;
            C[(size_t)row * 512 + col] = f2b(v);
        }
    }
}

// ---------------- Sparse attention: keys = {0} ∪ [start[i], i-1], one wave per (token i, head h)
// Round-5 structure (no cross-iteration prefetch — it spilled) + 4-way split
// accumulators in QK and PV to break the dependent-FMA chains (scalars only, no spill risk).
__global__ __launch_bounds__(256) void attn_kernel(
    const ushort_t* __restrict__ Q, const ushort_t* __restrict__ K,
    const ushort_t* __restrict__ V, const int* __restrict__ START,
    ushort_t* __restrict__ O)
{
    __shared__ ushort_t Vs[4][64 * 66];   // stride 66: conflict-free (measured 0 conflicts)
    __shared__ float ps[4][64];

    int w = threadIdx.x >> 6;
    int lane = threadIdx.x & 63;
    int wid = blockIdx.x * 4 + w;
    int i = wid >> 3;
    int h = wid & 7;

    float qv = b2f(Q[(size_t)i * 512 + h * 64 + lane]) * 0.125f;  // fold 1/sqrt(64)
    int si = START[i];
    if (si < 1) si = 1;
    if (si > i) si = i;
    int nk = (i == 0) ? 1 : (i - si + 1);

    float m_run = -INFINITY, l_run = 0.f;
    float oa0 = 0.f, oa1 = 0.f, oa2 = 0.f, oa3 = 0.f;

    for (int t0 = 0; t0 < nk; t0 += 64) {
        int t = t0 + lane;
        bool valid = t < nk;
        int j = (t == 0) ? 0 : (si + t - 1);
        if (!valid) j = 0;
        if (j < 0) j = 0; if (j > L_TOK - 1) j = L_TOK - 1;

        // K-row and V-row loads issued together (16 independent 16B loads in flight)
        const uint4* kp = reinterpret_cast<const uint4*>(&K[(size_t)j * 512 + h * 64]);
        const uint4* vp = reinterpret_cast<const uint4*>(&V[(size_t)j * 512 + h * 64]);
        uint4 kr[8];
        uint4 vr[8];
#pragma unroll
        for (int c = 0; c < 8; c++) kr[c] = kp[c];
#pragma unroll
        for (int c = 0; c < 8; c++) vr[c] = vp[c];

        // QK dot: 4 independent accumulators (chains of 16 FMAs instead of 128)
        float sa0 = 0.f, sa1 = 0.f, sa2 = 0.f, sa3 = 0.f;
#pragma unroll
        for (int c = 0; c < 8; c++) {
            uint_t uu[4] = {kr[c].x, kr[c].y, kr[c].z, kr[c].w};
            float part = 0.f;
#pragma unroll
            for (int p2 = 0; p2 < 4; p2++) {
                int d = c * 8 + p2 * 2;
                part += __shfl(qv, d) * b2f((ushort_t)(uu[p2] & 0xffffu));
                part += __shfl(qv, d + 1) * b2f((ushort_t)(uu[p2] >> 16));
            }
            if ((c & 3) == 0) sa0 += part;
            else if ((c & 3) == 1) sa1 += part;
            else if ((c & 3) == 2) sa2 += part;
            else sa3 += part;
        }
        float s = (sa0 + sa1) + (sa2 + sa3);
        if (!valid) s = -INFINITY;

        // Stash V row to LDS (vr dead after this)
#pragma unroll
        for (int c = 0; c < 8; c++)
            *reinterpret_cast<uint4*>(&Vs[w][lane * 66 + c * 8]) = vr[c];

        // Online softmax
        float tmax = s;
#pragma unroll
        for (int off = 32; off > 0; off >>= 1) tmax = fmaxf(tmax, __shfl_xor(tmax, off));
        float m_new = fmaxf(m_run, tmax);
        float p = valid ? __expf(s - m_new) : 0.f;
        float psum = p;
#pragma unroll
        for (int off = 32; off > 0; off >>= 1) psum += __shfl_xor(psum, off);
        float alpha = (m_run == -INFINITY) ? 0.f : __expf(m_run - m_new);
        l_run = l_run * alpha + psum;
        oa0 *= alpha; oa1 *= alpha; oa2 *= alpha; oa3 *= alpha;

        ps[w][lane] = p;    // invalid lanes hold 0 -> full-64 PV loop needs no bound

        // PV: 4 independent accumulators (chains of 16 instead of 64)
#pragma unroll
        for (int j2 = 0; j2 < 64; j2 += 4) {
            oa0 += ps[w][j2 + 0] * b2f(Vs[w][(j2 + 0) * 66 + lane]);
            oa1 += ps[w][j2 + 1] * b2f(Vs[w][(j2 + 1) * 66 + lane]);
            oa2 += ps[w][j2 + 2] * b2f(Vs[w][(j2 + 2) * 66 + lane]);
            oa3 += ps[w][j2 + 3] * b2f(Vs[w][(j2 + 3) * 66 + lane]);
        }
        m_run = m_new;
    }
    float o_acc = (oa0 + oa1) + (oa2 + oa3);
    float inv = (l_run > 0.f) ? (1.f / l_run) : 0.f;
    O[(size_t)i * 512 + h * 64 + lane] = f2b(o_acc * inv);
}

// ---------------- LayerNorm (one wave per token); RESID adds R; F32OUT selects output format
template<int RESID, int F32OUT>
__global__ __launch_bounds__(256) void ln_kernel(
    const ushort_t* __restrict__ X, const ushort_t* __restrict__ R,
    const float* __restrict__ g, const float* __restrict__ be,
    void* __restrict__ outv)
{
    int tok = blockIdx.x * 4 + (threadIdx.x >> 6);
    int lane = threadIdx.x & 63;
    size_t base = (size_t)tok * 512 + lane * 8;

    float v[8];
    {
        uint4 ux = *reinterpret_cast<const uint4*>(&X[base]);
        uint_t ua[4] = {ux.x, ux.y, ux.z, ux.w};
#pragma unroll
        for (int p = 0; p < 4; p++) {
            v[2 * p] = b2f((ushort_t)(ua[p] & 0xffffu));
            v[2 * p + 1] = b2f((ushort_t)(ua[p] >> 16));
        }
        if (RESID) {
            uint4 ur = *reinterpret_cast<const uint4*>(&R[base]);
            uint_t ub[4] = {ur.x, ur.y, ur.z, ur.w};
#pragma unroll
            for (int p = 0; p < 4; p++) {
                v[2 * p] += b2f((ushort_t)(ub[p] & 0xffffu));
                v[2 * p + 1] += b2f((ushort_t)(ub[p] >> 16));
            }
        }
    }
    float sum = 0.f;
#pragma unroll
    for (int j = 0; j < 8; j++) sum += v[j];
#pragma unroll
    for (int off = 32; off > 0; off >>= 1) sum += __shfl_xor(sum, off);
    float mu = sum * (1.f / 512.f);
    float var = 0.f;
#pragma unroll
    for (int j = 0; j < 8; j++) { float d = v[j] - mu; var += d * d; }
#pragma unroll
    for (int off = 32; off > 0; off >>= 1) var += __shfl_xor(var, off);
    float rstd = rsqrtf(var * (1.f / 512.f) + 1e-5f);

    const float4* gp = reinterpret_cast<const float4*>(g);
    const float4* bp = reinterpret_cast<const float4*>(be);
    float4 g0 = gp[2 * lane], g1 = gp[2 * lane + 1];
    float4 b0 = bp[2 * lane], b1 = bp[2 * lane + 1];
    float gg[8] = {g0.x, g0.y, g0.z, g0.w, g1.x, g1.y, g1.z, g1.w};
    float bb[8] = {b0.x, b0.y, b0.z, b0.w, b1.x, b1.y, b1.z, b1.w};

    float o[8];
#pragma unroll
    for (int j = 0; j < 8; j++) o[j] = (v[j] - mu) * rstd * gg[j] + bb[j];

    if (F32OUT) {
        float* outf = (float*)outv;
        float4 o0 = {o[0], o[1], o[2], o[3]};
        float4 o1 = {o[4], o[5], o[6], o[7]};
        *reinterpret_cast<float4*>(&outf[base]) = o0;
        *reinterpret_cast<float4*>(&outf[base + 4]) = o1;
    } else {
        ushort_t* outb = (ushort_t*)outv;
        uint_t outp[4];
#pragma unroll
        for (int p = 0; p < 4; p++)
            outp[p] = (uint_t)f2b(o[2 * p]) | ((uint_t)f2b(o[2 * p + 1]) << 16);
        uint4 ov; ov.x = outp[0]; ov.y = outp[1]; ov.z = outp[2]; ov.w = outp[3];
        *reinterpret_cast<uint4*>(&outb[base]) = ov;
    }
}

extern "C" void kernel_launch(void* const* d_in, const int* in_sizes, int n_in,
                              void* d_out, int out_size, void* d_ws, size_t ws_size,
                              hipStream_t stream) {
    const int*   idx = (const int*)d_in[0];
    const int*   seq = (const int*)d_in[1];
    const float* Wt  = (const float*)d_in[2];
    const float* bt  = (const float*)d_in[3];
    const float* Wa  = (const float*)d_in[4];
    const float* ba  = (const float*)d_in[5];
    const float* Wm  = (const float*)d_in[6];
    const float* bm  = (const float*)d_in[7];
    const float* sos = (const float*)d_in[8];
    const float* Wq  = (const float*)d_in[9];
    const float* bq  = (const float*)d_in[10];
    const float* Wk  = (const float*)d_in[11];
    const float* bk  = (const float*)d_in[12];
    const float* Wv  = (const float*)d_in[13];
    const float* bv  = (const float*)d_in[14];
    const float* Wo  = (const float*)d_in[15];
    const float* bo  = (const float*)d_in[16];
    const float* W1  = (const float*)d_in[17];
    const float* b1  = (const float*)d_in[18];
    const float* W2  = (const float*)d_in[19];
    const float* b2  = (const float*)d_in[20];
    const float* g1  = (const float*)d_in[21];
    const float* be1 = (const float*)d_in[22];
    const float* g2  = (const float*)d_in[23];
    const float* be2 = (const float*)d_in[24];

    const size_t NB = (size_t)L_TOK * DMODEL;

    int* START = (int*)d_ws;
    ushort_t* WB = (ushort_t*)d_ws + 16384;
    ushort_t* WQc = WB + 0 * WELEM;
    ushort_t* WKc = WB + 1 * WELEM;
    ushort_t* WVc = WB + 2 * WELEM;
    ushort_t* WOc = WB + 3 * WELEM;
    ushort_t* W1c = WB + 4 * WELEM;
    ushort_t* W2c = WB + 5 * WELEM;
    ushort_t* bufs = WB + 6 * WELEM;
    ushort_t* B0 = bufs;            // X / attn-out / next-layer X
    ushort_t* B1 = bufs + 1 * NB;   // Q / O-proj out / FF hidden
    ushort_t* B2 = bufs + 2 * NB;   // K / XA
    ushort_t* B3 = bufs + 3 * NB;   // V / FF2 out

    convert_weights<<<1536, 256, 0, stream>>>(Wq, Wk, Wv, Wo, W1, W2, WB);
    embed_kernel<<<6144, 256, 0, stream>>>(idx, Wt, bt, Wa, ba, Wm, bm, sos, B0);
    scan_start<<<1, 1024, 0, stream>>>(seq, START);

    for (int layer = 0; layer < 2; layer++) {
        gemm512<0><<<dim3(48, 8, 3), 256, 0, stream>>>(B0, WQc, WKc, WVc, bq, bk, bv, B1, B2, B3);
        attn_kernel<<<6144, 256, 0, stream>>>(B1, B2, B3, START, B0);
        gemm512<0><<<dim3(48, 8, 1), 256, 0, stream>>>(B0, WOc, WOc, WOc, bo, bo, bo, B1, B1, B1);
        ln_kernel<0, 0><<<768, 256, 0, stream>>>(B1, B1, g1, be1, B2);          // XA -> B2
        gemm512<1><<<dim3(48, 8, 1), 256, 0, stream>>>(B2, W1c, W1c, W1c, b1, b1, b1, B1, B1, B1);
        gemm512<0><<<dim3(48, 8, 1), 256, 0, stream>>>(B1, W2c, W2c, W2c, b2, b2, b2, B3, B3, B3);
        if (layer == 0)
            ln_kernel<1, 0><<<768, 256, 0, stream>>>(B3, B2, g2, be2, B0);      // bf16 internal
        else
            ln_kernel<1, 1><<<768, 256, 0, stream>>>(B3, B2, g2, be2, d_out);   // fp32 final output
    }
}

// Round 8
// 371.741 us; speedup vs baseline: 1.7593x; 1.0618x over previous
//
#include <hip/hip_runtime.h>

typedef unsigned short ushort_t;
typedef unsigned int uint_t;

#define L_TOK 3072
#define DMODEL 512
#define WELEM 262144   // 512*512

using bf16x8 = __attribute__((ext_vector_type(8))) short;
using f32x4  = __attribute__((ext_vector_type(4))) float;

__device__ __forceinline__ float b2f(ushort_t u) {
    union { uint_t i; float f; } c; c.i = ((uint_t)u) << 16; return c.f;
}
__device__ __forceinline__ ushort_t f2b(float f) {
    union { float f; uint_t i; } c; c.f = f;
    uint_t x = c.i;
    return (ushort_t)((x + 0x7fffu + ((x >> 16) & 1u)) >> 16);  // RNE
}

// ---------------- Fused prologue: blocks [0,1536) convert weights, [1536,7680) embed,
// block 7680 computes start[] scan. One dispatch instead of three.
__global__ __launch_bounds__(256) void prologue_kernel(
    const float* __restrict__ Wq, const float* __restrict__ Wk, const float* __restrict__ Wv,
    const float* __restrict__ Wo, const float* __restrict__ W1, const float* __restrict__ W2,
    ushort_t* __restrict__ WB,
    const int* __restrict__ idx,
    const float* __restrict__ Wt, const float* __restrict__ bt,
    const float* __restrict__ Wa, const float* __restrict__ ba,
    const float* __restrict__ Wm, const float* __restrict__ bm,
    const float* __restrict__ sos, ushort_t* __restrict__ X,
    const int* __restrict__ seq, int* __restrict__ start)
{
    __shared__ int sbuf0[256];
    __shared__ int sbuf1[256];
    int bid = blockIdx.x;
    int tid = threadIdx.x;

    if (bid < 1536) {
        // ---- weight convert: 6 matrices fp32 -> bf16, 4 floats/thread
        int gid = bid * 256 + tid;
        int mat = gid >> 16;
        int off = (gid & 65535) * 4;
        const float* src;
        switch (mat) {
            case 0: src = Wq; break;
            case 1: src = Wk; break;
            case 2: src = Wv; break;
            case 3: src = Wo; break;
            case 4: src = W1; break;
            default: src = W2; break;
        }
        float4 v = *reinterpret_cast<const float4*>(src + off);
        uint2 o;
        o.x = (uint_t)f2b(v.x) | ((uint_t)f2b(v.y) << 16);
        o.y = (uint_t)f2b(v.z) | ((uint_t)f2b(v.w) << 16);
        *reinterpret_cast<uint2*>(&WB[mat * WELEM + off]) = o;
    } else if (bid < 7680) {
        // ---- embedding: x[0]=sos, x[1+n] = Wt[:,t]+bt + Wa[:,a]+ba + Wm[:,m]+bm
        int gid = (bid - 1536) * 256 + tid;    // 3072*512 total
        int tok = gid >> 9;
        int d = gid & 511;
        float val;
        if (tok == 0) {
            val = sos[d];
        } else {
            int id = idx[tok - 1];
            int t = id / 219;            // 73*3
            int a = (id / 3) % 73;
            int m = id % 3;
            val = Wt[d * 15 + t] + bt[d]
                + Wa[d * 73 + a] + ba[d]
                + Wm[d * 3 + m] + bm[d];
        }
        X[gid] = f2b(val);
    } else {
        // ---- start[] scan: inclusive max-scan of boundary(i) over 3072, 12 chunks of 256
        // boundary(i): i==0 -> 0, i==1 -> 1, i>=2 -> (seq[i-1]==0 ? i : 0)
        int carry = 0;
        for (int c = 0; c < 12; c++) {
            int i = c * 256 + tid;
            int b;
            if (i <= 1) b = i;
            else b = (seq[i - 1] == 0) ? i : 0;
            sbuf0[tid] = b;
            __syncthreads();
            int* src = sbuf0;
            int* dst = sbuf1;
            for (int off = 1; off < 256; off <<= 1) {
                int v = src[tid];
                if (tid >= off) { int u = src[tid - off]; if (u > v) v = u; }
                dst[tid] = v;
                __syncthreads();
                int* t = src; src = dst; dst = t;
            }
            int val = src[tid] > carry ? src[tid] : carry;
            start[i] = val;
            int tot = src[255] > carry ? src[255] : carry;
            __syncthreads();   // all reads of src done before next chunk overwrites sbuf0
            carry = tot;
        }
    }
}

// ---------------- GEMM: C[3072,512] = A@W^T + bias; A,W,C bf16, bias fp32, fp32 acc
// 64x64 tile, 4 waves, mfma 16x16x32 bf16 (verified layout — unchanged since round 4)
template<int RELU>
__global__ __launch_bounds__(256) void gemm512(
    const ushort_t* __restrict__ A,
    const ushort_t* __restrict__ Wp0, const ushort_t* __restrict__ Wp1, const ushort_t* __restrict__ Wp2,
    const float* __restrict__ bp0, const float* __restrict__ bp1, const float* __restrict__ bp2,
    ushort_t* __restrict__ Cp0, ushort_t* __restrict__ Cp1, ushort_t* __restrict__ Cp2)
{
    const ushort_t* W = Wp0; const float* bias = bp0; ushort_t* C = Cp0;
    if (blockIdx.z == 1) { W = Wp1; bias = bp1; C = Cp1; }
    else if (blockIdx.z == 2) { W = Wp2; bias = bp2; C = Cp2; }

    __shared__ ushort_t As[64 * 72];
    __shared__ ushort_t Bs[64 * 72];

    const int tid = threadIdx.x;
    const int lane = tid & 63;
    const int w = tid >> 6;
    const int lm = lane & 15;
    const int q4 = lane >> 4;

    const int m0 = blockIdx.x * 64;
    const int n0 = blockIdx.y * 64;

    f32x4 acc[4];
#pragma unroll
    for (int i = 0; i < 4; i++) acc[i] = (f32x4){0.f, 0.f, 0.f, 0.f};

    for (int k0 = 0; k0 < 512; k0 += 64) {
        for (int c = tid; c < 512; c += 256) {
            int row = c >> 3, col = (c & 7) << 3;
            uint4 va = *reinterpret_cast<const uint4*>(&A[(size_t)(m0 + row) * 512 + k0 + col]);
            *reinterpret_cast<uint4*>(&As[row * 72 + col]) = va;
            uint4 vb = *reinterpret_cast<const uint4*>(&W[(size_t)(n0 + row) * 512 + k0 + col]);
            *reinterpret_cast<uint4*>(&Bs[row * 72 + col]) = vb;
        }
        __syncthreads();
#pragma unroll
        for (int kk = 0; kk < 64; kk += 32) {
            bf16x8 af = *reinterpret_cast<const bf16x8*>(&As[(w * 16 + lm) * 72 + kk + q4 * 8]);
#pragma unroll
            for (int nt = 0; nt < 4; nt++) {
                bf16x8 bf = *reinterpret_cast<const bf16x8*>(&Bs[(nt * 16 + lm) * 72 + kk + q4 * 8]);
                acc[nt] = __builtin_amdgcn_mfma_f32_16x16x32_bf16(af, bf, acc[nt], 0, 0, 0);
            }
        }
        __syncthreads();
    }

#pragma unroll
    for (int nt = 0; nt < 4; nt++) {
        int col = n0 + nt * 16 + lm;
        float bv = bias[col];
#pragma unroll
        for (int r = 0; r < 4; r++) {
            int row = m0 + w * 16 + q4 * 4 + r;
            float v = acc[nt][r] + bv;
            if (RELU) v = (v > 0.f) ? v : 0.01f * v;
            C[(size_t)row * 512 + col] = f2b(v);
        }
    }
}

// ---------------- Sparse attention: keys = {0} ∪ [start[i], i-1], one wave per (token i, head h)
// Round-5 arithmetic (known good). Changes: 2-wave blocks (LDS 17.4 KB -> 9 blocks/CU = 18
// waves/CU, up from 16) and reverse-token ordering (heaviest blocks dispatch first, LPT-style).
__global__ __launch_bounds__(128) void attn_kernel(
    const ushort_t* __restrict__ Q, const ushort_t* __restrict__ K,
    const ushort_t* __restrict__ V, const int* __restrict__ START,
    ushort_t* __restrict__ O)
{
    __shared__ ushort_t Vs[2][64 * 66];   // stride 66: conflict-free (measured 0 conflicts)
    __shared__ float ps[2][64];

    int w = threadIdx.x >> 6;
    int lane = threadIdx.x & 63;
    int gwid = blockIdx.x * 2 + w;
    int i = (L_TOK - 1) - (gwid >> 3);    // reverse order: big-nk tokens first
    int h = gwid & 7;

    float qv = b2f(Q[(size_t)i * 512 + h * 64 + lane]) * 0.125f;  // fold 1/sqrt(64)
    int si = START[i];
    if (si < 1) si = 1;
    if (si > i) si = i;
    int nk = (i == 0) ? 1 : (i - si + 1);

    float m_run = -INFINITY, l_run = 0.f, o_acc = 0.f;

    for (int t0 = 0; t0 < nk; t0 += 64) {
        int t = t0 + lane;
        bool valid = t < nk;
        int j = (t == 0) ? 0 : (si + t - 1);
        if (!valid) j = 0;
        if (j < 0) j = 0; if (j > L_TOK - 1) j = L_TOK - 1;

        // K-row and V-row loads issued together (16 independent 16B loads in flight)
        const uint4* kp = reinterpret_cast<const uint4*>(&K[(size_t)j * 512 + h * 64]);
        const uint4* vp = reinterpret_cast<const uint4*>(&V[(size_t)j * 512 + h * 64]);
        uint4 kr[8];
        uint4 vr[8];
#pragma unroll
        for (int c = 0; c < 8; c++) kr[c] = kp[c];
#pragma unroll
        for (int c = 0; c < 8; c++) vr[c] = vp[c];

        // QK dot: lane j owns key j; q broadcast via shfl (compile-time lane index)
        float s = 0.f;
#pragma unroll
        for (int c = 0; c < 8; c++) {
            uint_t uu[4] = {kr[c].x, kr[c].y, kr[c].z, kr[c].w};
#pragma unroll
            for (int p2 = 0; p2 < 4; p2++) {
                int d = c * 8 + p2 * 2;
                s += __shfl(qv, d) * b2f((ushort_t)(uu[p2] & 0xffffu));
                s += __shfl(qv, d + 1) * b2f((ushort_t)(uu[p2] >> 16));
            }
        }
        if (!valid) s = -INFINITY;

        // Stash V row to LDS (vr dead after this)
#pragma unroll
        for (int c = 0; c < 8; c++)
            *reinterpret_cast<uint4*>(&Vs[w][lane * 66 + c * 8]) = vr[c];

        // Online softmax
        float tmax = s;
#pragma unroll
        for (int off = 32; off > 0; off >>= 1) tmax = fmaxf(tmax, __shfl_xor(tmax, off));
        float m_new = fmaxf(m_run, tmax);
        float p = valid ? __expf(s - m_new) : 0.f;
        float psum = p;
#pragma unroll
        for (int off = 32; off > 0; off >>= 1) psum += __shfl_xor(psum, off);
        float alpha = (m_run == -INFINITY) ? 0.f : __expf(m_run - m_new);
        l_run = l_run * alpha + psum;
        o_acc *= alpha;

        ps[w][lane] = p;    // invalid lanes hold 0 -> full-64 PV loop needs no bound

        // PV: o[lane] += sum_j p_j * V[j][lane]; broadcast ps read + conflict-free Vs read
#pragma unroll
        for (int j2 = 0; j2 < 64; j2++) {
            float pj = ps[w][j2];
            o_acc += pj * b2f(Vs[w][j2 * 66 + lane]);
        }
        m_run = m_new;
    }
    float inv = (l_run > 0.f) ? (1.f / l_run) : 0.f;
    O[(size_t)i * 512 + h * 64 + lane] = f2b(o_acc * inv);
}

// ---------------- LayerNorm (one wave per token); RESID adds R; F32OUT selects output format
template<int RESID, int F32OUT>
__global__ __launch_bounds__(256) void ln_kernel(
    const ushort_t* __restrict__ X, const ushort_t* __restrict__ R,
    const float* __restrict__ g, const float* __restrict__ be,
    void* __restrict__ outv)
{
    int tok = blockIdx.x * 4 + (threadIdx.x >> 6);
    int lane = threadIdx.x & 63;
    size_t base = (size_t)tok * 512 + lane * 8;

    float v[8];
    {
        uint4 ux = *reinterpret_cast<const uint4*>(&X[base]);
        uint_t ua[4] = {ux.x, ux.y, ux.z, ux.w};
#pragma unroll
        for (int p = 0; p < 4; p++) {
            v[2 * p] = b2f((ushort_t)(ua[p] & 0xffffu));
            v[2 * p + 1] = b2f((ushort_t)(ua[p] >> 16));
        }
        if (RESID) {
            uint4 ur = *reinterpret_cast<const uint4*>(&R[base]);
            uint_t ub[4] = {ur.x, ur.y, ur.z, ur.w};
#pragma unroll
            for (int p = 0; p < 4; p++) {
                v[2 * p] += b2f((ushort_t)(ub[p] & 0xffffu));
                v[2 * p + 1] += b2f((ushort_t)(ub[p] >> 16));
            }
        }
    }
    float sum = 0.f;
#pragma unroll
    for (int j = 0; j < 8; j++) sum += v[j];
#pragma unroll
    for (int off = 32; off > 0; off >>= 1) sum += __shfl_xor(sum, off);
    float mu = sum * (1.f / 512.f);
    float var = 0.f;
#pragma unroll
    for (int j = 0; j < 8; j++) { float d = v[j] - mu; var += d * d; }
#pragma unroll
    for (int off = 32; off > 0; off >>= 1) var += __shfl_xor(var, off);
    float rstd = rsqrtf(var * (1.f / 512.f) + 1e-5f);

    const float4* gp = reinterpret_cast<const float4*>(g);
    const float4* bp = reinterpret_cast<const float4*>(be);
    float4 g0 = gp[2 * lane], g1 = gp[2 * lane + 1];
    float4 b0 = bp[2 * lane], b1 = bp[2 * lane + 1];
    float gg[8] = {g0.x, g0.y, g0.z, g0.w, g1.x, g1.y, g1.z, g1.w};
    float bb[8] = {b0.x, b0.y, b0.z, b0.w, b1.x, b1.y, b1.z, b1.w};

    float o[8];
#pragma unroll
    for (int j = 0; j < 8; j++) o[j] = (v[j] - mu) * rstd * gg[j] + bb[j];

    if (F32OUT) {
        float* outf = (float*)outv;
        float4 o0 = {o[0], o[1], o[2], o[3]};
        float4 o1 = {o[4], o[5], o[6], o[7]};
        *reinterpret_cast<float4*>(&outf[base]) = o0;
        *reinterpret_cast<float4*>(&outf[base + 4]) = o1;
    } else {
        ushort_t* outb = (ushort_t*)outv;
        uint_t outp[4];
#pragma unroll
        for (int p = 0; p < 4; p++)
            outp[p] = (uint_t)f2b(o[2 * p]) | ((uint_t)f2b(o[2 * p + 1]) << 16);
        uint4 ov; ov.x = outp[0]; ov.y = outp[1]; ov.z = outp[2]; ov.w = outp[3];
        *reinterpret_cast<uint4*>(&outb[base]) = ov;
    }
}

extern "C" void kernel_launch(void* const* d_in, const int* in_sizes, int n_in,
                              void* d_out, int out_size, void* d_ws, size_t ws_size,
                              hipStream_t stream) {
    const int*   idx = (const int*)d_in[0];
    const int*   seq = (const int*)d_in[1];
    const float* Wt  = (const float*)d_in[2];
    const float* bt  = (const float*)d_in[3];
    const float* Wa  = (const float*)d_in[4];
    const float* ba  = (const float*)d_in[5];
    const float* Wm  = (const float*)d_in[6];
    const float* bm  = (const float*)d_in[7];
    const float* sos = (const float*)d_in[8];
    const float* Wq  = (const float*)d_in[9];
    const float* bq  = (const float*)d_in[10];
    const float* Wk  = (const float*)d_in[11];
    const float* bk  = (const float*)d_in[12];
    const float* Wv  = (const float*)d_in[13];
    const float* bv  = (const float*)d_in[14];
    const float* Wo  = (const float*)d_in[15];
    const float* bo  = (const float*)d_in[16];
    const float* W1  = (const float*)d_in[17];
    const float* b1  = (const float*)d_in[18];
    const float* W2  = (const float*)d_in[19];
    const float* b2  = (const float*)d_in[20];
    const float* g1  = (const float*)d_in[21];
    const float* be1 = (const float*)d_in[22];
    const float* g2  = (const float*)d_in[23];
    const float* be2 = (const float*)d_in[24];

    const size_t NB = (size_t)L_TOK * DMODEL;

    int* START = (int*)d_ws;
    ushort_t* WB = (ushort_t*)d_ws + 16384;
    ushort_t* WQc = WB + 0 * WELEM;
    ushort_t* WKc = WB + 1 * WELEM;
    ushort_t* WVc = WB + 2 * WELEM;
    ushort_t* WOc = WB + 3 * WELEM;
    ushort_t* W1c = WB + 4 * WELEM;
    ushort_t* W2c = WB + 5 * WELEM;
    ushort_t* bufs = WB + 6 * WELEM;
    ushort_t* B0 = bufs;            // X / attn-out / next-layer X
    ushort_t* B1 = bufs + 1 * NB;   // Q / O-proj out / FF hidden
    ushort_t* B2 = bufs + 2 * NB;   // K / XA
    ushort_t* B3 = bufs + 3 * NB;   // V / FF2 out

    prologue_kernel<<<7681, 256, 0, stream>>>(
        Wq, Wk, Wv, Wo, W1, W2, WB,
        idx, Wt, bt, Wa, ba, Wm, bm, sos, B0,
        seq, START);

    for (int layer = 0; layer < 2; layer++) {
        gemm512<0><<<dim3(48, 8, 3), 256, 0, stream>>>(B0, WQc, WKc, WVc, bq, bk, bv, B1, B2, B3);
        attn_kernel<<<12288, 128, 0, stream>>>(B1, B2, B3, START, B0);
        gemm512<0><<<dim3(48, 8, 1), 256, 0, stream>>>(B0, WOc, WOc, WOc, bo, bo, bo, B1, B1, B1);
        ln_kernel<0, 0><<<768, 256, 0, stream>>>(B1, B1, g1, be1, B2);          // XA -> B2
        gemm512<1><<<dim3(48, 8, 1), 256, 0, stream>>>(B2, W1c, W1c, W1c, b1, b1, b1, B1, B1, B1);
        gemm512<0><<<dim3(48, 8, 1), 256, 0, stream>>>(B1, W2c, W2c, W2c, b2, b2, b2, B3, B3, B3);
        if (layer == 0)
            ln_kernel<1, 0><<<768, 256, 0, stream>>>(B3, B2, g2, be2, B0);      // bf16 internal
        else
            ln_kernel<1, 1><<<768, 256, 0, stream>>>(B3, B2, g2, be2, d_out);   // fp32 final output
    }
}

// Round 9
// 275.522 us; speedup vs baseline: 2.3737x; 1.3492x over previous
//
#include <hip/hip_runtime.h>

typedef unsigned short ushort_t;
typedef unsigned int uint_t;

#define L_TOK 3072
#define DMODEL 512
#define WELEM 262144   // 512*512

using bf16x8 = __attribute__((ext_vector_type(8))) short;
using f32x4  = __attribute__((ext_vector_type(4))) float;

__device__ __forceinline__ float b2f(ushort_t u) {
    union { uint_t i; float f; } c; c.i = ((uint_t)u) << 16; return c.f;
}
__device__ __forceinline__ ushort_t f2b(float f) {
    union { float f; uint_t i; } c; c.f = f;
    uint_t x = c.i;
    return (ushort_t)((x + 0x7fffu + ((x >> 16) & 1u)) >> 16);  // RNE
}

// ---------------- Fused prologue: blocks [0,1536) convert weights, [1536,7680) embed,
// block 7680 computes start[] scan.
__global__ __launch_bounds__(256) void prologue_kernel(
    const float* __restrict__ Wq, const float* __restrict__ Wk, const float* __restrict__ Wv,
    const float* __restrict__ Wo, const float* __restrict__ W1, const float* __restrict__ W2,
    ushort_t* __restrict__ WB,
    const int* __restrict__ idx,
    const float* __restrict__ Wt, const float* __restrict__ bt,
    const float* __restrict__ Wa, const float* __restrict__ ba,
    const float* __restrict__ Wm, const float* __restrict__ bm,
    const float* __restrict__ sos, ushort_t* __restrict__ X,
    const int* __restrict__ seq, int* __restrict__ start)
{
    __shared__ int sbuf0[256];
    __shared__ int sbuf1[256];
    int bid = blockIdx.x;
    int tid = threadIdx.x;

    if (bid < 1536) {
        int gid = bid * 256 + tid;
        int mat = gid >> 16;
        int off = (gid & 65535) * 4;
        const float* src;
        switch (mat) {
            case 0: src = Wq; break;
            case 1: src = Wk; break;
            case 2: src = Wv; break;
            case 3: src = Wo; break;
            case 4: src = W1; break;
            default: src = W2; break;
        }
        float4 v = *reinterpret_cast<const float4*>(src + off);
        uint2 o;
        o.x = (uint_t)f2b(v.x) | ((uint_t)f2b(v.y) << 16);
        o.y = (uint_t)f2b(v.z) | ((uint_t)f2b(v.w) << 16);
        *reinterpret_cast<uint2*>(&WB[mat * WELEM + off]) = o;
    } else if (bid < 7680) {
        int gid = (bid - 1536) * 256 + tid;    // 3072*512 total
        int tok = gid >> 9;
        int d = gid & 511;
        float val;
        if (tok == 0) {
            val = sos[d];
        } else {
            int id = idx[tok - 1];
            int t = id / 219;            // 73*3
            int a = (id / 3) % 73;
            int m = id % 3;
            val = Wt[d * 15 + t] + bt[d]
                + Wa[d * 73 + a] + ba[d]
                + Wm[d * 3 + m] + bm[d];
        }
        X[gid] = f2b(val);
    } else {
        // start[] scan: inclusive max-scan of boundary(i) over 3072, 12 chunks of 256
        int carry = 0;
        for (int c = 0; c < 12; c++) {
            int i = c * 256 + tid;
            int b;
            if (i <= 1) b = i;
            else b = (seq[i - 1] == 0) ? i : 0;
            sbuf0[tid] = b;
            __syncthreads();
            int* src = sbuf0;
            int* dst = sbuf1;
            for (int off = 1; off < 256; off <<= 1) {
                int v = src[tid];
                if (tid >= off) { int u = src[tid - off]; if (u > v) v = u; }
                dst[tid] = v;
                __syncthreads();
                int* t = src; src = dst; dst = t;
            }
            int val = src[tid] > carry ? src[tid] : carry;
            start[i] = val;
            int tot = src[255] > carry ? src[255] : carry;
            __syncthreads();
            carry = tot;
        }
    }
}

// ---------------- GEMM: C[3072,512] = A@W^T + bias (verified, unchanged since round 4)
template<int RELU>
__global__ __launch_bounds__(256) void gemm512(
    const ushort_t* __restrict__ A,
    const ushort_t* __restrict__ Wp0, const ushort_t* __restrict__ Wp1, const ushort_t* __restrict__ Wp2,
    const float* __restrict__ bp0, const float* __restrict__ bp1, const float* __restrict__ bp2,
    ushort_t* __restrict__ Cp0, ushort_t* __restrict__ Cp1, ushort_t* __restrict__ Cp2)
{
    const ushort_t* W = Wp0; const float* bias = bp0; ushort_t* C = Cp0;
    if (blockIdx.z == 1) { W = Wp1; bias = bp1; C = Cp1; }
    else if (blockIdx.z == 2) { W = Wp2; bias = bp2; C = Cp2; }

    __shared__ ushort_t As[64 * 72];
    __shared__ ushort_t Bs[64 * 72];

    const int tid = threadIdx.x;
    const int lane = tid & 63;
    const int w = tid >> 6;
    const int lm = lane & 15;
    const int q4 = lane >> 4;

    const int m0 = blockIdx.x * 64;
    const int n0 = blockIdx.y * 64;

    f32x4 acc[4];
#pragma unroll
    for (int i = 0; i < 4; i++) acc[i] = (f32x4){0.f, 0.f, 0.f, 0.f};

    for (int k0 = 0; k0 < 512; k0 += 64) {
        for (int c = tid; c < 512; c += 256) {
            int row = c >> 3, col = (c & 7) << 3;
            uint4 va = *reinterpret_cast<const uint4*>(&A[(size_t)(m0 + row) * 512 + k0 + col]);
            *reinterpret_cast<uint4*>(&As[row * 72 + col]) = va;
            uint4 vb = *reinterpret_cast<const uint4*>(&W[(size_t)(n0 + row) * 512 + k0 + col]);
            *reinterpret_cast<uint4*>(&Bs[row * 72 + col]) = vb;
        }
        __syncthreads();
#pragma unroll
        for (int kk = 0; kk < 64; kk += 32) {
            bf16x8 af = *reinterpret_cast<const bf16x8*>(&As[(w * 16 + lm) * 72 + kk + q4 * 8]);
#pragma unroll
            for (int nt = 0; nt < 4; nt++) {
                bf16x8 bf = *reinterpret_cast<const bf16x8*>(&Bs[(nt * 16 + lm) * 72 + kk + q4 * 8]);
                acc[nt] = __builtin_amdgcn_mfma_f32_16x16x32_bf16(af, bf, acc[nt], 0, 0, 0);
            }
        }
        __syncthreads();
    }

#pragma unroll
    for (int nt = 0; nt < 4; nt++) {
        int col = n0 + nt * 16 + lm;
        float bv = bias[col];
#pragma unroll
        for (int r = 0; r < 4; r++) {
            int row = m0 + w * 16 + q4 * 4 + r;
            float v = acc[nt][r] + bv;
            if (RELU) v = (v > 0.f) ? v : 0.01f * v;
            C[(size_t)row * 512 + col] = f2b(v);
        }
    }
}

// ---------------- MFMA flash attention: one wave per (16-query tile, head).
// Keys for query i: {0} ∪ [start[i], i-1]. Chunk enumerates t=0..nk-1 with
// token(t) = (t==0) ? 0 : lo+t-1, lo = max(1, start[i0]); per-element mask
// valid(q, jj) = (jj==0) | (s_q <= jj < i_q) handles batch-boundary tiles.
// Fragment layouts copied from verified gemm512; P goes C-layout -> LDS -> A-layout.
// Wave-private LDS tiles: no barriers anywhere.
__global__ __launch_bounds__(256) void attn_mfma(
    const ushort_t* __restrict__ Q, const ushort_t* __restrict__ K,
    const ushort_t* __restrict__ V, const int* __restrict__ START,
    ushort_t* __restrict__ O)
{
    __shared__ ushort_t VtS[4][64 * 72];   // V^T [dim][key], per wave
    __shared__ ushort_t PsS[4][16 * 72];   // P [query][key], per wave

    int w = threadIdx.x >> 6;
    int lane = threadIdx.x & 63;
    ushort_t* Vt = VtS[w];
    ushort_t* Ps = PsS[w];

    int gw = blockIdx.x * 4 + w;          // 1536 units
    int tile = 191 - (gw >> 3);           // reverse: long-range tiles first (LPT)
    int h = gw & 7;
    int i0 = tile * 16;
    int lm = lane & 15;
    int q4 = lane >> 4;

    // Per-row query info: rows r=0..3 -> query i0 + q4*4 + r
    int iq0 = i0 + q4 * 4;
    int sq[4];
#pragma unroll
    for (int r = 0; r < 4; r++) sq[r] = START[iq0 + r];

    int lo = START[i0]; if (lo < 1) lo = 1;
    int nk = i0 + 16 - lo;                // keys: slot 0 = token 0, slots 1.. = lo..i0+14

    // Q A-fragments (held all kernel): m=lm (query), k = kk*32 + q4*8 + j
    const ushort_t* Qp = Q + (size_t)(i0 + lm) * 512 + h * 64 + q4 * 8;
    bf16x8 aQ0 = *reinterpret_cast<const bf16x8*>(Qp);
    bf16x8 aQ1 = *reinterpret_cast<const bf16x8*>(Qp + 32);

    float m_run[4], l_run[4];
    f32x4 oacc[4];
#pragma unroll
    for (int r = 0; r < 4; r++) { m_run[r] = -INFINITY; l_run[r] = 0.f; }
#pragma unroll
    for (int nt = 0; nt < 4; nt++) oacc[nt] = (f32x4){0.f, 0.f, 0.f, 0.f};

    for (int t0 = 0; t0 < nk; t0 += 64) {
        // ---- V row for key_local = lane
        int tv = t0 + lane;
        int jv = (tv == 0) ? 0 : (lo + tv - 1);
        if (jv > L_TOK - 1) jv = L_TOK - 1;
        const uint4* vp = reinterpret_cast<const uint4*>(&V[(size_t)jv * 512 + h * 64]);
        uint4 vr[8];
#pragma unroll
        for (int c = 0; c < 8; c++) vr[c] = vp[c];

        // ---- QK^T: 8 MFMAs; K B-fragments straight from global (n=lm -> key, k=q4*8+j)
        int jn[4];
#pragma unroll
        for (int nt = 0; nt < 4; nt++) {
            int t = t0 + nt * 16 + lm;
            jn[nt] = (t == 0) ? 0 : (lo + t - 1);   // unclamped (mask uses this)
        }
        f32x4 sacc[4];
#pragma unroll
        for (int nt = 0; nt < 4; nt++) sacc[nt] = (f32x4){0.f, 0.f, 0.f, 0.f};
#pragma unroll
        for (int nt = 0; nt < 4; nt++) {
            int jc = jn[nt] > L_TOK - 1 ? L_TOK - 1 : jn[nt];
            const ushort_t* Kp = K + (size_t)jc * 512 + h * 64 + q4 * 8;
            bf16x8 bK0 = *reinterpret_cast<const bf16x8*>(Kp);
            bf16x8 bK1 = *reinterpret_cast<const bf16x8*>(Kp + 32);
            sacc[nt] = __builtin_amdgcn_mfma_f32_16x16x32_bf16(aQ0, bK0, sacc[nt], 0, 0, 0);
            sacc[nt] = __builtin_amdgcn_mfma_f32_16x16x32_bf16(aQ1, bK1, sacc[nt], 0, 0, 0);
        }

        // ---- transpose V into Vt[dim][key] (2-way dword aliasing only -> free)
#pragma unroll
        for (int c = 0; c < 8; c++) {
            uint_t ww[4] = {vr[c].x, vr[c].y, vr[c].z, vr[c].w};
#pragma unroll
            for (int e = 0; e < 4; e++) {
                int d0 = c * 8 + e * 2;
                Vt[d0 * 72 + lane] = (ushort_t)(ww[e] & 0xffffu);
                Vt[(d0 + 1) * 72 + lane] = (ushort_t)(ww[e] >> 16);
            }
        }

        // ---- scale + mask (element (nt,r): query iq0+r, key token jn[nt])
#pragma unroll
        for (int nt = 0; nt < 4; nt++) {
            int jju = jn[nt];
#pragma unroll
            for (int r = 0; r < 4; r++) {
                float s = sacc[nt][r] * 0.125f;
                bool val = (jju == 0) || (sq[r] <= jju && jju < iq0 + r);
                sacc[nt][r] = val ? s : -INFINITY;
            }
        }

        // ---- online softmax row stats (reduce over 16 lanes sharing q4)
        float mnew[4], alpha[4];
#pragma unroll
        for (int r = 0; r < 4; r++) {
            float mx = fmaxf(fmaxf(sacc[0][r], sacc[1][r]), fmaxf(sacc[2][r], sacc[3][r]));
            mx = fmaxf(mx, __shfl_xor(mx, 1));
            mx = fmaxf(mx, __shfl_xor(mx, 2));
            mx = fmaxf(mx, __shfl_xor(mx, 4));
            mx = fmaxf(mx, __shfl_xor(mx, 8));
            float mn = fmaxf(m_run[r], mx);      // finite from chunk 0 (key 0 valid for all rows)
            mnew[r] = mn;
            alpha[r] = __expf(m_run[r] - mn);    // exp(-inf) = 0 on first chunk
        }

        // ---- p = exp(s - m), write P[query][key] to LDS, accumulate row sums
#pragma unroll
        for (int r = 0; r < 4; r++) {
            float rs = 0.f;
#pragma unroll
            for (int nt = 0; nt < 4; nt++) {
                float p = __expf(sacc[nt][r] - mnew[r]);   // masked -> 0
                rs += p;
                Ps[(q4 * 4 + r) * 72 + nt * 16 + lm] = f2b(p);
            }
            rs += __shfl_xor(rs, 1);
            rs += __shfl_xor(rs, 2);
            rs += __shfl_xor(rs, 4);
            rs += __shfl_xor(rs, 8);
            l_run[r] = l_run[r] * alpha[r] + rs;
            m_run[r] = mnew[r];
        }
#pragma unroll
        for (int nt = 0; nt < 4; nt++)
#pragma unroll
            for (int r = 0; r < 4; r++) oacc[nt][r] *= alpha[r];

        // ---- PV: P A-frags (m=lm query, k=key), V^T B-frags (n=lm dim, k=key); 8 MFMAs
        bf16x8 aP0 = *reinterpret_cast<const bf16x8*>(&Ps[lm * 72 + q4 * 8]);
        bf16x8 aP1 = *reinterpret_cast<const bf16x8*>(&Ps[lm * 72 + 32 + q4 * 8]);
#pragma unroll
        for (int nt = 0; nt < 4; nt++) {
            bf16x8 bV0 = *reinterpret_cast<const bf16x8*>(&Vt[(nt * 16 + lm) * 72 + q4 * 8]);
            bf16x8 bV1 = *reinterpret_cast<const bf16x8*>(&Vt[(nt * 16 + lm) * 72 + 32 + q4 * 8]);
            oacc[nt] = __builtin_amdgcn_mfma_f32_16x16x32_bf16(aP0, bV0, oacc[nt], 0, 0, 0);
            oacc[nt] = __builtin_amdgcn_mfma_f32_16x16x32_bf16(aP1, bV1, oacc[nt], 0, 0, 0);
        }
    }

    // ---- epilogue: O[query][h*64+dim] = oacc / l  (C-layout, same as gemm512 epilogue)
#pragma unroll
    for (int r = 0; r < 4; r++) {
        float inv = (l_run[r] > 0.f) ? (1.f / l_run[r]) : 0.f;
#pragma unroll
        for (int nt = 0; nt < 4; nt++)
            O[(size_t)(iq0 + r) * 512 + h * 64 + nt * 16 + lm] = f2b(oacc[nt][r] * inv);
    }
}

// ---------------- LayerNorm (one wave per token); RESID adds R; F32OUT selects output format
template<int RESID, int F32OUT>
__global__ __launch_bounds__(256) void ln_kernel(
    const ushort_t* __restrict__ X, const ushort_t* __restrict__ R,
    const float* __restrict__ g, const float* __restrict__ be,
    void* __restrict__ outv)
{
    int tok = blockIdx.x * 4 + (threadIdx.x >> 6);
    int lane = threadIdx.x & 63;
    size_t base = (size_t)tok * 512 + lane * 8;

    float v[8];
    {
        uint4 ux = *reinterpret_cast<const uint4*>(&X[base]);
        uint_t ua[4] = {ux.x, ux.y, ux.z, ux.w};
#pragma unroll
        for (int p = 0; p < 4; p++) {
            v[2 * p] = b2f((ushort_t)(ua[p] & 0xffffu));
            v[2 * p + 1] = b2f((ushort_t)(ua[p] >> 16));
        }
        if (RESID) {
            uint4 ur = *reinterpret_cast<const uint4*>(&R[base]);
            uint_t ub[4] = {ur.x, ur.y, ur.z, ur.w};
#pragma unroll
            for (int p = 0; p < 4; p++) {
                v[2 * p] += b2f((ushort_t)(ub[p] & 0xffffu));
                v[2 * p + 1] += b2f((ushort_t)(ub[p] >> 16));
            }
        }
    }
    float sum = 0.f;
#pragma unroll
    for (int j = 0; j < 8; j++) sum += v[j];
#pragma unroll
    for (int off = 32; off > 0; off >>= 1) sum += __shfl_xor(sum, off);
    float mu = sum * (1.f / 512.f);
    float var = 0.f;
#pragma unroll
    for (int j = 0; j < 8; j++) { float d = v[j] - mu; var += d * d; }
#pragma unroll
    for (int off = 32; off > 0; off >>= 1) var += __shfl_xor(var, off);
    float rstd = rsqrtf(var * (1.f / 512.f) + 1e-5f);

    const float4* gp = reinterpret_cast<const float4*>(g);
    const float4* bp = reinterpret_cast<const float4*>(be);
    float4 g0 = gp[2 * lane], g1 = gp[2 * lane + 1];
    float4 b0 = bp[2 * lane], b1 = bp[2 * lane + 1];
    float gg[8] = {g0.x, g0.y, g0.z, g0.w, g1.x, g1.y, g1.z, g1.w};
    float bb[8] = {b0.x, b0.y, b0.z, b0.w, b1.x, b1.y, b1.z, b1.w};

    float o[8];
#pragma unroll
    for (int j = 0; j < 8; j++) o[j] = (v[j] - mu) * rstd * gg[j] + bb[j];

    if (F32OUT) {
        float* outf = (float*)outv;
        float4 o0 = {o[0], o[1], o[2], o[3]};
        float4 o1 = {o[4], o[5], o[6], o[7]};
        *reinterpret_cast<float4*>(&outf[base]) = o0;
        *reinterpret_cast<float4*>(&outf[base + 4]) = o1;
    } else {
        ushort_t* outb = (ushort_t*)outv;
        uint_t outp[4];
#pragma unroll
        for (int p = 0; p < 4; p++)
            outp[p] = (uint_t)f2b(o[2 * p]) | ((uint_t)f2b(o[2 * p + 1]) << 16);
        uint4 ov; ov.x = outp[0]; ov.y = outp[1]; ov.z = outp[2]; ov.w = outp[3];
        *reinterpret_cast<uint4*>(&outb[base]) = ov;
    }
}

extern "C" void kernel_launch(void* const* d_in, const int* in_sizes, int n_in,
                              void* d_out, int out_size, void* d_ws, size_t ws_size,
                              hipStream_t stream) {
    const int*   idx = (const int*)d_in[0];
    const int*   seq = (const int*)d_in[1];
    const float* Wt  = (const float*)d_in[2];
    const float* bt  = (const float*)d_in[3];
    const float* Wa  = (const float*)d_in[4];
    const float* ba  = (const float*)d_in[5];
    const float* Wm  = (const float*)d_in[6];
    const float* bm  = (const float*)d_in[7];
    const float* sos = (const float*)d_in[8];
    const float* Wq  = (const float*)d_in[9];
    const float* bq  = (const float*)d_in[10];
    const float* Wk  = (const float*)d_in[11];
    const float* bk  = (const float*)d_in[12];
    const float* Wv  = (const float*)d_in[13];
    const float* bv  = (const float*)d_in[14];
    const float* Wo  = (const float*)d_in[15];
    const float* bo  = (const float*)d_in[16];
    const float* W1  = (const float*)d_in[17];
    const float* b1  = (const float*)d_in[18];
    const float* W2  = (const float*)d_in[19];
    const float* b2  = (const float*)d_in[20];
    const float* g1  = (const float*)d_in[21];
    const float* be1 = (const float*)d_in[22];
    const float* g2  = (const float*)d_in[23];
    const float* be2 = (const float*)d_in[24];

    const size_t NB = (size_t)L_TOK * DMODEL;

    int* START = (int*)d_ws;
    ushort_t* WB = (ushort_t*)d_ws + 16384;
    ushort_t* WQc = WB + 0 * WELEM;
    ushort_t* WKc = WB + 1 * WELEM;
    ushort_t* WVc = WB + 2 * WELEM;
    ushort_t* WOc = WB + 3 * WELEM;
    ushort_t* W1c = WB + 4 * WELEM;
    ushort_t* W2c = WB + 5 * WELEM;
    ushort_t* bufs = WB + 6 * WELEM;
    ushort_t* B0 = bufs;            // X / attn-out / next-layer X
    ushort_t* B1 = bufs + 1 * NB;   // Q / O-proj out / FF hidden
    ushort_t* B2 = bufs + 2 * NB;   // K / XA
    ushort_t* B3 = bufs + 3 * NB;   // V / FF2 out

    prologue_kernel<<<7681, 256, 0, stream>>>(
        Wq, Wk, Wv, Wo, W1, W2, WB,
        idx, Wt, bt, Wa, ba, Wm, bm, sos, B0,
        seq, START);

    for (int layer = 0; layer < 2; layer++) {
        gemm512<0><<<dim3(48, 8, 3), 256, 0, stream>>>(B0, WQc, WKc, WVc, bq, bk, bv, B1, B2, B3);
        attn_mfma<<<384, 256, 0, stream>>>(B1, B2, B3, START, B0);
        gemm512<0><<<dim3(48, 8, 1), 256, 0, stream>>>(B0, WOc, WOc, WOc, bo, bo, bo, B1, B1, B1);
        ln_kernel<0, 0><<<768, 256, 0, stream>>>(B1, B1, g1, be1, B2);          // XA -> B2
        gemm512<1><<<dim3(48, 8, 1), 256, 0, stream>>>(B2, W1c, W1c, W1c, b1, b1, b1, B1, B1, B1);
        gemm512<0><<<dim3(48, 8, 1), 256, 0, stream>>>(B1, W2c, W2c, W2c, b2, b2, b2, B3, B3, B3);
        if (layer == 0)
            ln_kernel<1, 0><<<768, 256, 0, stream>>>(B3, B2, g2, be2, B0);      // bf16 internal
        else
            ln_kernel<1, 1><<<768, 256, 0, stream>>>(B3, B2, g2, be2, d_out);   // fp32 final output
    }
}

// Round 10
// 253.927 us; speedup vs baseline: 2.5756x; 1.0850x over previous
//
#include <hip/hip_runtime.h>

typedef unsigned short ushort_t;
typedef unsigned int uint_t;

#define L_TOK 3072
#define DMODEL 512
#define WELEM 262144   // 512*512

using bf16x8 = __attribute__((ext_vector_type(8))) short;
using f32x4  = __attribute__((ext_vector_type(4))) float;

__device__ __forceinline__ float b2f(ushort_t u) {
    union { uint_t i; float f; } c; c.i = ((uint_t)u) << 16; return c.f;
}
__device__ __forceinline__ ushort_t f2b(float f) {
    union { float f; uint_t i; } c; c.f = f;
    uint_t x = c.i;
    return (ushort_t)((x + 0x7fffu + ((x >> 16) & 1u)) >> 16);  // RNE
}

// ---------------- Fused prologue: blocks [0,1536) convert weights, [1536,7680) embed,
// block 7680 computes start[] scan.
__global__ __launch_bounds__(256) void prologue_kernel(
    const float* __restrict__ Wq, const float* __restrict__ Wk, const float* __restrict__ Wv,
    const float* __restrict__ Wo, const float* __restrict__ W1, const float* __restrict__ W2,
    ushort_t* __restrict__ WB,
    const int* __restrict__ idx,
    const float* __restrict__ Wt, const float* __restrict__ bt,
    const float* __restrict__ Wa, const float* __restrict__ ba,
    const float* __restrict__ Wm, const float* __restrict__ bm,
    const float* __restrict__ sos, ushort_t* __restrict__ X,
    const int* __restrict__ seq, int* __restrict__ start)
{
    __shared__ int sbuf0[256];
    __shared__ int sbuf1[256];
    int bid = blockIdx.x;
    int tid = threadIdx.x;

    if (bid < 1536) {
        int gid = bid * 256 + tid;
        int mat = gid >> 16;
        int off = (gid & 65535) * 4;
        const float* src;
        switch (mat) {
            case 0: src = Wq; break;
            case 1: src = Wk; break;
            case 2: src = Wv; break;
            case 3: src = Wo; break;
            case 4: src = W1; break;
            default: src = W2; break;
        }
        float4 v = *reinterpret_cast<const float4*>(src + off);
        uint2 o;
        o.x = (uint_t)f2b(v.x) | ((uint_t)f2b(v.y) << 16);
        o.y = (uint_t)f2b(v.z) | ((uint_t)f2b(v.w) << 16);
        *reinterpret_cast<uint2*>(&WB[mat * WELEM + off]) = o;
    } else if (bid < 7680) {
        int gid = (bid - 1536) * 256 + tid;    // 3072*512 total
        int tok = gid >> 9;
        int d = gid & 511;
        float val;
        if (tok == 0) {
            val = sos[d];
        } else {
            int id = idx[tok - 1];
            int t = id / 219;            // 73*3
            int a = (id / 3) % 73;
            int m = id % 3;
            val = Wt[d * 15 + t] + bt[d]
                + Wa[d * 73 + a] + ba[d]
                + Wm[d * 3 + m] + bm[d];
        }
        X[gid] = f2b(val);
    } else {
        // start[] scan: inclusive max-scan of boundary(i) over 3072, 12 chunks of 256
        int carry = 0;
        for (int c = 0; c < 12; c++) {
            int i = c * 256 + tid;
            int b;
            if (i <= 1) b = i;
            else b = (seq[i - 1] == 0) ? i : 0;
            sbuf0[tid] = b;
            __syncthreads();
            int* src = sbuf0;
            int* dst = sbuf1;
            for (int off = 1; off < 256; off <<= 1) {
                int v = src[tid];
                if (tid >= off) { int u = src[tid - off]; if (u > v) v = u; }
                dst[tid] = v;
                __syncthreads();
                int* t = src; src = dst; dst = t;
            }
            int val = src[tid] > carry ? src[tid] : carry;
            start[i] = val;
            int tot = src[255] > carry ? src[255] : carry;
            __syncthreads();
            carry = tot;
        }
    }
}

// ---------------- GEMM: C[3072,512] = A@W^T + bias; software-pipelined double-buffer.
// At 1.5 blocks/CU there are no other waves to hide staging latency behind, so the
// K-loop prefetches tile k+1 into registers BEFORE the MFMA section consumes tile k
// (vmcnt wait lands at the ds_write after the MFMAs). Single barrier per iteration,
// fully unrolled (all LDS indices compile-time). Fragment layout unchanged (verified).
template<int RELU>
__global__ __launch_bounds__(256) void gemm512(
    const ushort_t* __restrict__ A,
    const ushort_t* __restrict__ Wp0, const ushort_t* __restrict__ Wp1, const ushort_t* __restrict__ Wp2,
    const float* __restrict__ bp0, const float* __restrict__ bp1, const float* __restrict__ bp2,
    ushort_t* __restrict__ Cp0, ushort_t* __restrict__ Cp1, ushort_t* __restrict__ Cp2)
{
    const ushort_t* W = Wp0; const float* bias = bp0; ushort_t* C = Cp0;
    if (blockIdx.z == 1) { W = Wp1; bias = bp1; C = Cp1; }
    else if (blockIdx.z == 2) { W = Wp2; bias = bp2; C = Cp2; }

    __shared__ ushort_t As[2 * 64 * 72];   // ping-pong tiles, +8 pad per row
    __shared__ ushort_t Bs[2 * 64 * 72];

    const int tid = threadIdx.x;
    const int lane = tid & 63;
    const int w = tid >> 6;
    const int lm = lane & 15;
    const int q4 = lane >> 4;

    const int m0 = blockIdx.x * 64;
    const int n0 = blockIdx.y * 64;

    // Staging split: thread owns chunks tid and tid+256 of 512 16B-chunks per tile.
    const int row0 = tid >> 3;              // 0..31
    const int colc = (tid & 7) << 3;        // 0..56
    const ushort_t* Arow0 = A + (size_t)(m0 + row0) * 512 + colc;
    const ushort_t* Arow1 = Arow0 + (size_t)32 * 512;
    const ushort_t* Brow0 = W + (size_t)(n0 + row0) * 512 + colc;
    const ushort_t* Brow1 = Brow0 + (size_t)32 * 512;
    const int lds0 = row0 * 72 + colc;
    const int lds1 = (row0 + 32) * 72 + colc;

    f32x4 acc[4];
#pragma unroll
    for (int i = 0; i < 4; i++) acc[i] = (f32x4){0.f, 0.f, 0.f, 0.f};

    // Preload tile 0 -> regs -> LDS[0]
    uint4 a0 = *reinterpret_cast<const uint4*>(Arow0);
    uint4 a1 = *reinterpret_cast<const uint4*>(Arow1);
    uint4 b0 = *reinterpret_cast<const uint4*>(Brow0);
    uint4 b1 = *reinterpret_cast<const uint4*>(Brow1);
    *reinterpret_cast<uint4*>(&As[lds0]) = a0;
    *reinterpret_cast<uint4*>(&As[lds1]) = a1;
    *reinterpret_cast<uint4*>(&Bs[lds0]) = b0;
    *reinterpret_cast<uint4*>(&Bs[lds1]) = b1;
    __syncthreads();

#pragma unroll
    for (int it = 0; it < 8; it++) {
        const int cur = (it & 1) * 4608;
        const int alt = ((it & 1) ^ 1) * 4608;
        const int nxt = (it + 1) * 64;

        // Issue next tile's global loads first (completion awaited at ds_write below)
        uint4 na0, na1, nb0, nb1;
        if (it < 7) {
            na0 = *reinterpret_cast<const uint4*>(Arow0 + nxt);
            na1 = *reinterpret_cast<const uint4*>(Arow1 + nxt);
            nb0 = *reinterpret_cast<const uint4*>(Brow0 + nxt);
            nb1 = *reinterpret_cast<const uint4*>(Brow1 + nxt);
        }

        // MFMAs on current tile
#pragma unroll
        for (int kk = 0; kk < 64; kk += 32) {
            bf16x8 af = *reinterpret_cast<const bf16x8*>(&As[cur + (w * 16 + lm) * 72 + kk + q4 * 8]);
#pragma unroll
            for (int nt = 0; nt < 4; nt++) {
                bf16x8 bf = *reinterpret_cast<const bf16x8*>(&Bs[cur + (nt * 16 + lm) * 72 + kk + q4 * 8]);
                acc[nt] = __builtin_amdgcn_mfma_f32_16x16x32_bf16(af, bf, acc[nt], 0, 0, 0);
            }
        }

        // Stage next tile into the other buffer
        if (it < 7) {
            *reinterpret_cast<uint4*>(&As[alt + lds0]) = na0;
            *reinterpret_cast<uint4*>(&As[alt + lds1]) = na1;
            *reinterpret_cast<uint4*>(&Bs[alt + lds0]) = nb0;
            *reinterpret_cast<uint4*>(&Bs[alt + lds1]) = nb1;
            __syncthreads();
        }
    }

#pragma unroll
    for (int nt = 0; nt < 4; nt++) {
        int col = n0 + nt * 16 + lm;
        float bv = bias[col];
#pragma unroll
        for (int r = 0; r < 4; r++) {
            int row = m0 + w * 16 + q4 * 4 + r;
            float v = acc[nt][r] + bv;
            if (RELU) v = (v > 0.f) ? v : 0.01f * v;
            C[(size_t)row * 512 + col] = f2b(v);
        }
    }
}

// ---------------- MFMA flash attention (verified round 9, unchanged)
__global__ __launch_bounds__(256) void attn_mfma(
    const ushort_t* __restrict__ Q, const ushort_t* __restrict__ K,
    const ushort_t* __restrict__ V, const int* __restrict__ START,
    ushort_t* __restrict__ O)
{
    __shared__ ushort_t VtS[4][64 * 72];   // V^T [dim][key], per wave
    __shared__ ushort_t PsS[4][16 * 72];   // P [query][key], per wave

    int w = threadIdx.x >> 6;
    int lane = threadIdx.x & 63;
    ushort_t* Vt = VtS[w];
    ushort_t* Ps = PsS[w];

    int gw = blockIdx.x * 4 + w;          // 1536 units
    int tile = 191 - (gw >> 3);           // reverse: long-range tiles first (LPT)
    int h = gw & 7;
    int i0 = tile * 16;
    int lm = lane & 15;
    int q4 = lane >> 4;

    int iq0 = i0 + q4 * 4;
    int sq[4];
#pragma unroll
    for (int r = 0; r < 4; r++) sq[r] = START[iq0 + r];

    int lo = START[i0]; if (lo < 1) lo = 1;
    int nk = i0 + 16 - lo;

    const ushort_t* Qp = Q + (size_t)(i0 + lm) * 512 + h * 64 + q4 * 8;
    bf16x8 aQ0 = *reinterpret_cast<const bf16x8*>(Qp);
    bf16x8 aQ1 = *reinterpret_cast<const bf16x8*>(Qp + 32);

    float m_run[4], l_run[4];
    f32x4 oacc[4];
#pragma unroll
    for (int r = 0; r < 4; r++) { m_run[r] = -INFINITY; l_run[r] = 0.f; }
#pragma unroll
    for (int nt = 0; nt < 4; nt++) oacc[nt] = (f32x4){0.f, 0.f, 0.f, 0.f};

    for (int t0 = 0; t0 < nk; t0 += 64) {
        int tv = t0 + lane;
        int jv = (tv == 0) ? 0 : (lo + tv - 1);
        if (jv > L_TOK - 1) jv = L_TOK - 1;
        const uint4* vp = reinterpret_cast<const uint4*>(&V[(size_t)jv * 512 + h * 64]);
        uint4 vr[8];
#pragma unroll
        for (int c = 0; c < 8; c++) vr[c] = vp[c];

        int jn[4];
#pragma unroll
        for (int nt = 0; nt < 4; nt++) {
            int t = t0 + nt * 16 + lm;
            jn[nt] = (t == 0) ? 0 : (lo + t - 1);
        }
        f32x4 sacc[4];
#pragma unroll
        for (int nt = 0; nt < 4; nt++) sacc[nt] = (f32x4){0.f, 0.f, 0.f, 0.f};
#pragma unroll
        for (int nt = 0; nt < 4; nt++) {
            int jc = jn[nt] > L_TOK - 1 ? L_TOK - 1 : jn[nt];
            const ushort_t* Kp = K + (size_t)jc * 512 + h * 64 + q4 * 8;
            bf16x8 bK0 = *reinterpret_cast<const bf16x8*>(Kp);
            bf16x8 bK1 = *reinterpret_cast<const bf16x8*>(Kp + 32);
            sacc[nt] = __builtin_amdgcn_mfma_f32_16x16x32_bf16(aQ0, bK0, sacc[nt], 0, 0, 0);
            sacc[nt] = __builtin_amdgcn_mfma_f32_16x16x32_bf16(aQ1, bK1, sacc[nt], 0, 0, 0);
        }

#pragma unroll
        for (int c = 0; c < 8; c++) {
            uint_t ww[4] = {vr[c].x, vr[c].y, vr[c].z, vr[c].w};
#pragma unroll
            for (int e = 0; e < 4; e++) {
                int d0 = c * 8 + e * 2;
                Vt[d0 * 72 + lane] = (ushort_t)(ww[e] & 0xffffu);
                Vt[(d0 + 1) * 72 + lane] = (ushort_t)(ww[e] >> 16);
            }
        }

#pragma unroll
        for (int nt = 0; nt < 4; nt++) {
            int jju = jn[nt];
#pragma unroll
            for (int r = 0; r < 4; r++) {
                float s = sacc[nt][r] * 0.125f;
                bool val = (jju == 0) || (sq[r] <= jju && jju < iq0 + r);
                sacc[nt][r] = val ? s : -INFINITY;
            }
        }

        float mnew[4], alpha[4];
#pragma unroll
        for (int r = 0; r < 4; r++) {
            float mx = fmaxf(fmaxf(sacc[0][r], sacc[1][r]), fmaxf(sacc[2][r], sacc[3][r]));
            mx = fmaxf(mx, __shfl_xor(mx, 1));
            mx = fmaxf(mx, __shfl_xor(mx, 2));
            mx = fmaxf(mx, __shfl_xor(mx, 4));
            mx = fmaxf(mx, __shfl_xor(mx, 8));
            float mn = fmaxf(m_run[r], mx);
            mnew[r] = mn;
            alpha[r] = __expf(m_run[r] - mn);
        }

#pragma unroll
        for (int r = 0; r < 4; r++) {
            float rs = 0.f;
#pragma unroll
            for (int nt = 0; nt < 4; nt++) {
                float p = __expf(sacc[nt][r] - mnew[r]);
                rs += p;
                Ps[(q4 * 4 + r) * 72 + nt * 16 + lm] = f2b(p);
            }
            rs += __shfl_xor(rs, 1);
            rs += __shfl_xor(rs, 2);
            rs += __shfl_xor(rs, 4);
            rs += __shfl_xor(rs, 8);
            l_run[r] = l_run[r] * alpha[r] + rs;
            m_run[r] = mnew[r];
        }
#pragma unroll
        for (int nt = 0; nt < 4; nt++)
#pragma unroll
            for (int r = 0; r < 4; r++) oacc[nt][r] *= alpha[r];

        bf16x8 aP0 = *reinterpret_cast<const bf16x8*>(&Ps[lm * 72 + q4 * 8]);
        bf16x8 aP1 = *reinterpret_cast<const bf16x8*>(&Ps[lm * 72 + 32 + q4 * 8]);
#pragma unroll
        for (int nt = 0; nt < 4; nt++) {
            bf16x8 bV0 = *reinterpret_cast<const bf16x8*>(&Vt[(nt * 16 + lm) * 72 + q4 * 8]);
            bf16x8 bV1 = *reinterpret_cast<const bf16x8*>(&Vt[(nt * 16 + lm) * 72 + 32 + q4 * 8]);
            oacc[nt] = __builtin_amdgcn_mfma_f32_16x16x32_bf16(aP0, bV0, oacc[nt], 0, 0, 0);
            oacc[nt] = __builtin_amdgcn_mfma_f32_16x16x32_bf16(aP1, bV1, oacc[nt], 0, 0, 0);
        }
    }

#pragma unroll
    for (int r = 0; r < 4; r++) {
        float inv = (l_run[r] > 0.f) ? (1.f / l_run[r]) : 0.f;
#pragma unroll
        for (int nt = 0; nt < 4; nt++)
            O[(size_t)(iq0 + r) * 512 + h * 64 + nt * 16 + lm] = f2b(oacc[nt][r] * inv);
    }
}

// ---------------- LayerNorm (one wave per token); RESID adds R; F32OUT selects output format
template<int RESID, int F32OUT>
__global__ __launch_bounds__(256) void ln_kernel(
    const ushort_t* __restrict__ X, const ushort_t* __restrict__ R,
    const float* __restrict__ g, const float* __restrict__ be,
    void* __restrict__ outv)
{
    int tok = blockIdx.x * 4 + (threadIdx.x >> 6);
    int lane = threadIdx.x & 63;
    size_t base = (size_t)tok * 512 + lane * 8;

    float v[8];
    {
        uint4 ux = *reinterpret_cast<const uint4*>(&X[base]);
        uint_t ua[4] = {ux.x, ux.y, ux.z, ux.w};
#pragma unroll
        for (int p = 0; p < 4; p++) {
            v[2 * p] = b2f((ushort_t)(ua[p] & 0xffffu));
            v[2 * p + 1] = b2f((ushort_t)(ua[p] >> 16));
        }
        if (RESID) {
            uint4 ur = *reinterpret_cast<const uint4*>(&R[base]);
            uint_t ub[4] = {ur.x, ur.y, ur.z, ur.w};
#pragma unroll
            for (int p = 0; p < 4; p++) {
                v[2 * p] += b2f((ushort_t)(ub[p] & 0xffffu));
                v[2 * p + 1] += b2f((ushort_t)(ub[p] >> 16));
            }
        }
    }
    float sum = 0.f;
#pragma unroll
    for (int j = 0; j < 8; j++) sum += v[j];
#pragma unroll
    for (int off = 32; off > 0; off >>= 1) sum += __shfl_xor(sum, off);
    float mu = sum * (1.f / 512.f);
    float var = 0.f;
#pragma unroll
    for (int j = 0; j < 8; j++) { float d = v[j] - mu; var += d * d; }
#pragma unroll
    for (int off = 32; off > 0; off >>= 1) var += __shfl_xor(var, off);
    float rstd = rsqrtf(var * (1.f / 512.f) + 1e-5f);

    const float4* gp = reinterpret_cast<const float4*>(g);
    const float4* bp = reinterpret_cast<const float4*>(be);
    float4 g0 = gp[2 * lane], g1 = gp[2 * lane + 1];
    float4 b0 = bp[2 * lane], b1 = bp[2 * lane + 1];
    float gg[8] = {g0.x, g0.y, g0.z, g0.w, g1.x, g1.y, g1.z, g1.w};
    float bb[8] = {b0.x, b0.y, b0.z, b0.w, b1.x, b1.y, b1.z, b1.w};

    float o[8];
#pragma unroll
    for (int j = 0; j < 8; j++) o[j] = (v[j] - mu) * rstd * gg[j] + bb[j];

    if (F32OUT) {
        float* outf = (float*)outv;
        float4 o0 = {o[0], o[1], o[2], o[3]};
        float4 o1 = {o[4], o[5], o[6], o[7]};
        *reinterpret_cast<float4*>(&outf[base]) = o0;
        *reinterpret_cast<float4*>(&outf[base + 4]) = o1;
    } else {
        ushort_t* outb = (ushort_t*)outv;
        uint_t outp[4];
#pragma unroll
        for (int p = 0; p < 4; p++)
            outp[p] = (uint_t)f2b(o[2 * p]) | ((uint_t)f2b(o[2 * p + 1]) << 16);
        uint4 ov; ov.x = outp[0]; ov.y = outp[1]; ov.z = outp[2]; ov.w = outp[3];
        *reinterpret_cast<uint4*>(&outb[base]) = ov;
    }
}

extern "C" void kernel_launch(void* const* d_in, const int* in_sizes, int n_in,
                              void* d_out, int out_size, void* d_ws, size_t ws_size,
                              hipStream_t stream) {
    const int*   idx = (const int*)d_in[0];
    const int*   seq = (const int*)d_in[1];
    const float* Wt  = (const float*)d_in[2];
    const float* bt  = (const float*)d_in[3];
    const float* Wa  = (const float*)d_in[4];
    const float* ba  = (const float*)d_in[5];
    const float* Wm  = (const float*)d_in[6];
    const float* bm  = (const float*)d_in[7];
    const float* sos = (const float*)d_in[8];
    const float* Wq  = (const float*)d_in[9];
    const float* bq  = (const float*)d_in[10];
    const float* Wk  = (const float*)d_in[11];
    const float* bk  = (const float*)d_in[12];
    const float* Wv  = (const float*)d_in[13];
    const float* bv  = (const float*)d_in[14];
    const float* Wo  = (const float*)d_in[15];
    const float* bo  = (const float*)d_in[16];
    const float* W1  = (const float*)d_in[17];
    const float* b1  = (const float*)d_in[18];
    const float* W2  = (const float*)d_in[19];
    const float* b2  = (const float*)d_in[20];
    const float* g1  = (const float*)d_in[21];
    const float* be1 = (const float*)d_in[22];
    const float* g2  = (const float*)d_in[23];
    const float* be2 = (const float*)d_in[24];

    const size_t NB = (size_t)L_TOK * DMODEL;

    int* START = (int*)d_ws;
    ushort_t* WB = (ushort_t*)d_ws + 16384;
    ushort_t* WQc = WB + 0 * WELEM;
    ushort_t* WKc = WB + 1 * WELEM;
    ushort_t* WVc = WB + 2 * WELEM;
    ushort_t* WOc = WB + 3 * WELEM;
    ushort_t* W1c = WB + 4 * WELEM;
    ushort_t* W2c = WB + 5 * WELEM;
    ushort_t* bufs = WB + 6 * WELEM;
    ushort_t* B0 = bufs;            // X / attn-out / next-layer X
    ushort_t* B1 = bufs + 1 * NB;   // Q / O-proj out / FF hidden
    ushort_t* B2 = bufs + 2 * NB;   // K / XA
    ushort_t* B3 = bufs + 3 * NB;   // V / FF2 out

    prologue_kernel<<<7681, 256, 0, stream>>>(
        Wq, Wk, Wv, Wo, W1, W2, WB,
        idx, Wt, bt, Wa, ba, Wm, bm, sos, B0,
        seq, START);

    for (int layer = 0; layer < 2; layer++) {
        gemm512<0><<<dim3(48, 8, 3), 256, 0, stream>>>(B0, WQc, WKc, WVc, bq, bk, bv, B1, B2, B3);
        attn_mfma<<<384, 256, 0, stream>>>(B1, B2, B3, START, B0);
        gemm512<0><<<dim3(48, 8, 1), 256, 0, stream>>>(B0, WOc, WOc, WOc, bo, bo, bo, B1, B1, B1);
        ln_kernel<0, 0><<<768, 256, 0, stream>>>(B1, B1, g1, be1, B2);          // XA -> B2
        gemm512<1><<<dim3(48, 8, 1), 256, 0, stream>>>(B2, W1c, W1c, W1c, b1, b1, b1, B1, B1, B1);
        gemm512<0><<<dim3(48, 8, 1), 256, 0, stream>>>(B1, W2c, W2c, W2c, b2, b2, b2, B3, B3, B3);
        if (layer == 0)
            ln_kernel<1, 0><<<768, 256, 0, stream>>>(B3, B2, g2, be2, B0);      // bf16 internal
        else
            ln_kernel<1, 1><<<768, 256, 0, stream>>>(B3, B2, g2, be2, d_out);   // fp32 final output
    }
}

// Round 11
// 253.498 us; speedup vs baseline: 2.5799x; 1.0017x over previous
//
#include <hip/hip_runtime.h>

typedef unsigned short ushort_t;
typedef unsigned int uint_t;

#define L_TOK 3072
#define DMODEL 512
#define WELEM 262144   // 512*512

using bf16x8 = __attribute__((ext_vector_type(8))) short;
using f32x4  = __attribute__((ext_vector_type(4))) float;

__device__ __forceinline__ float b2f(ushort_t u) {
    union { uint_t i; float f; } c; c.i = ((uint_t)u) << 16; return c.f;
}
__device__ __forceinline__ ushort_t f2b(float f) {
    union { float f; uint_t i; } c; c.f = f;
    uint_t x = c.i;
    return (ushort_t)((x + 0x7fffu + ((x >> 16) & 1u)) >> 16);  // RNE
}

// ---------------- Fused prologue: blocks [0,1536) convert weights, [1536,7680) embed,
// block 7680 computes start[] scan.
__global__ __launch_bounds__(256) void prologue_kernel(
    const float* __restrict__ Wq, const float* __restrict__ Wk, const float* __restrict__ Wv,
    const float* __restrict__ Wo, const float* __restrict__ W1, const float* __restrict__ W2,
    ushort_t* __restrict__ WB,
    const int* __restrict__ idx,
    const float* __restrict__ Wt, const float* __restrict__ bt,
    const float* __restrict__ Wa, const float* __restrict__ ba,
    const float* __restrict__ Wm, const float* __restrict__ bm,
    const float* __restrict__ sos, ushort_t* __restrict__ X,
    const int* __restrict__ seq, int* __restrict__ start)
{
    __shared__ int sbuf0[256];
    __shared__ int sbuf1[256];
    int bid = blockIdx.x;
    int tid = threadIdx.x;

    if (bid < 1536) {
        int gid = bid * 256 + tid;
        int mat = gid >> 16;
        int off = (gid & 65535) * 4;
        const float* src;
        switch (mat) {
            case 0: src = Wq; break;
            case 1: src = Wk; break;
            case 2: src = Wv; break;
            case 3: src = Wo; break;
            case 4: src = W1; break;
            default: src = W2; break;
        }
        float4 v = *reinterpret_cast<const float4*>(src + off);
        uint2 o;
        o.x = (uint_t)f2b(v.x) | ((uint_t)f2b(v.y) << 16);
        o.y = (uint_t)f2b(v.z) | ((uint_t)f2b(v.w) << 16);
        *reinterpret_cast<uint2*>(&WB[mat * WELEM + off]) = o;
    } else if (bid < 7680) {
        int gid = (bid - 1536) * 256 + tid;    // 3072*512 total
        int tok = gid >> 9;
        int d = gid & 511;
        float val;
        if (tok == 0) {
            val = sos[d];
        } else {
            int id = idx[tok - 1];
            int t = id / 219;            // 73*3
            int a = (id / 3) % 73;
            int m = id % 3;
            val = Wt[d * 15 + t] + bt[d]
                + Wa[d * 73 + a] + ba[d]
                + Wm[d * 3 + m] + bm[d];
        }
        X[gid] = f2b(val);
    } else {
        // start[] scan: inclusive max-scan of boundary(i) over 3072, 12 chunks of 256
        int carry = 0;
        for (int c = 0; c < 12; c++) {
            int i = c * 256 + tid;
            int b;
            if (i <= 1) b = i;
            else b = (seq[i - 1] == 0) ? i : 0;
            sbuf0[tid] = b;
            __syncthreads();
            int* src = sbuf0;
            int* dst = sbuf1;
            for (int off = 1; off < 256; off <<= 1) {
                int v = src[tid];
                if (tid >= off) { int u = src[tid - off]; if (u > v) v = u; }
                dst[tid] = v;
                __syncthreads();
                int* t = src; src = dst; dst = t;
            }
            int val = src[tid] > carry ? src[tid] : carry;
            start[i] = val;
            int tot = src[255] > carry ? src[255] : carry;
            __syncthreads();
            carry = tot;
        }
    }
}

// ---------------- GEMM: C[3072,512] = A@W^T + bias; 32x64 tile, 4 waves.
// Grid 96x8 = 768 blocks = exactly 3 blocks/CU (no quantization remainder),
// 12 waves/CU = 3/SIMD for latency hiding (vs 1.5 at the old 64x64 tiling).
// Wave w: rows (w&1)*16, cols (w>>1)*32; acc[2]; double-buffered K-loop
// (register prefetch of tile k+1 before MFMAs on tile k — kept from round 10).
template<int RELU>
__global__ __launch_bounds__(256) void gemm512(
    const ushort_t* __restrict__ A,
    const ushort_t* __restrict__ Wp0, const ushort_t* __restrict__ Wp1, const ushort_t* __restrict__ Wp2,
    const float* __restrict__ bp0, const float* __restrict__ bp1, const float* __restrict__ bp2,
    ushort_t* __restrict__ Cp0, ushort_t* __restrict__ Cp1, ushort_t* __restrict__ Cp2)
{
    const ushort_t* W = Wp0; const float* bias = bp0; ushort_t* C = Cp0;
    if (blockIdx.z == 1) { W = Wp1; bias = bp1; C = Cp1; }
    else if (blockIdx.z == 2) { W = Wp2; bias = bp2; C = Cp2; }

    __shared__ ushort_t As[2 * 32 * 72];   // ping-pong A tiles (32 rows)
    __shared__ ushort_t Bs[2 * 64 * 72];   // ping-pong B tiles (64 rows)

    const int tid = threadIdx.x;
    const int lane = tid & 63;
    const int w = tid >> 6;
    const int lm = lane & 15;
    const int q4 = lane >> 4;
    const int r0 = (w & 1) * 16;           // wave's row offset in tile
    const int c0 = (w >> 1) * 32;          // wave's col offset in tile

    const int m0 = blockIdx.x * 32;
    const int n0 = blockIdx.y * 64;

    // Staging: A tile = 256 16B-chunks (1/thread), B tile = 512 chunks (2/thread)
    const int srow = tid >> 3;              // 0..31
    const int scol = (tid & 7) << 3;        // 0..56
    const ushort_t* Arow = A + (size_t)(m0 + srow) * 512 + scol;
    const ushort_t* Brow0 = W + (size_t)(n0 + srow) * 512 + scol;
    const ushort_t* Brow1 = Brow0 + (size_t)32 * 512;
    const int ldsA = srow * 72 + scol;
    const int ldsB0 = srow * 72 + scol;
    const int ldsB1 = (srow + 32) * 72 + scol;

    f32x4 acc[2];
    acc[0] = (f32x4){0.f, 0.f, 0.f, 0.f};
    acc[1] = (f32x4){0.f, 0.f, 0.f, 0.f};

    // Preload tile 0
    uint4 a0 = *reinterpret_cast<const uint4*>(Arow);
    uint4 b0 = *reinterpret_cast<const uint4*>(Brow0);
    uint4 b1 = *reinterpret_cast<const uint4*>(Brow1);
    *reinterpret_cast<uint4*>(&As[ldsA]) = a0;
    *reinterpret_cast<uint4*>(&Bs[ldsB0]) = b0;
    *reinterpret_cast<uint4*>(&Bs[ldsB1]) = b1;
    __syncthreads();

#pragma unroll
    for (int it = 0; it < 8; it++) {
        const int curA = (it & 1) * 2304;
        const int altA = ((it & 1) ^ 1) * 2304;
        const int curB = (it & 1) * 4608;
        const int altB = ((it & 1) ^ 1) * 4608;
        const int nxt = (it + 1) * 64;

        uint4 na, nb0, nb1;
        if (it < 7) {
            na = *reinterpret_cast<const uint4*>(Arow + nxt);
            nb0 = *reinterpret_cast<const uint4*>(Brow0 + nxt);
            nb1 = *reinterpret_cast<const uint4*>(Brow1 + nxt);
        }

#pragma unroll
        for (int kk = 0; kk < 64; kk += 32) {
            bf16x8 af = *reinterpret_cast<const bf16x8*>(&As[curA + (r0 + lm) * 72 + kk + q4 * 8]);
#pragma unroll
            for (int nt = 0; nt < 2; nt++) {
                bf16x8 bf = *reinterpret_cast<const bf16x8*>(&Bs[curB + (c0 + nt * 16 + lm) * 72 + kk + q4 * 8]);
                acc[nt] = __builtin_amdgcn_mfma_f32_16x16x32_bf16(af, bf, acc[nt], 0, 0, 0);
            }
        }

        if (it < 7) {
            *reinterpret_cast<uint4*>(&As[altA + ldsA]) = na;
            *reinterpret_cast<uint4*>(&Bs[altB + ldsB0]) = nb0;
            *reinterpret_cast<uint4*>(&Bs[altB + ldsB1]) = nb1;
            __syncthreads();
        }
    }

#pragma unroll
    for (int nt = 0; nt < 2; nt++) {
        int col = n0 + c0 + nt * 16 + lm;
        float bv = bias[col];
#pragma unroll
        for (int r = 0; r < 4; r++) {
            int row = m0 + r0 + q4 * 4 + r;
            float v = acc[nt][r] + bv;
            if (RELU) v = (v > 0.f) ? v : 0.01f * v;
            C[(size_t)row * 512 + col] = f2b(v);
        }
    }
}

// ---------------- MFMA flash attention (verified round 9, unchanged)
__global__ __launch_bounds__(256) void attn_mfma(
    const ushort_t* __restrict__ Q, const ushort_t* __restrict__ K,
    const ushort_t* __restrict__ V, const int* __restrict__ START,
    ushort_t* __restrict__ O)
{
    __shared__ ushort_t VtS[4][64 * 72];   // V^T [dim][key], per wave
    __shared__ ushort_t PsS[4][16 * 72];   // P [query][key], per wave

    int w = threadIdx.x >> 6;
    int lane = threadIdx.x & 63;
    ushort_t* Vt = VtS[w];
    ushort_t* Ps = PsS[w];

    int gw = blockIdx.x * 4 + w;          // 1536 units
    int tile = 191 - (gw >> 3);           // reverse: long-range tiles first (LPT)
    int h = gw & 7;
    int i0 = tile * 16;
    int lm = lane & 15;
    int q4 = lane >> 4;

    int iq0 = i0 + q4 * 4;
    int sq[4];
#pragma unroll
    for (int r = 0; r < 4; r++) sq[r] = START[iq0 + r];

    int lo = START[i0]; if (lo < 1) lo = 1;
    int nk = i0 + 16 - lo;

    const ushort_t* Qp = Q + (size_t)(i0 + lm) * 512 + h * 64 + q4 * 8;
    bf16x8 aQ0 = *reinterpret_cast<const bf16x8*>(Qp);
    bf16x8 aQ1 = *reinterpret_cast<const bf16x8*>(Qp + 32);

    float m_run[4], l_run[4];
    f32x4 oacc[4];
#pragma unroll
    for (int r = 0; r < 4; r++) { m_run[r] = -INFINITY; l_run[r] = 0.f; }
#pragma unroll
    for (int nt = 0; nt < 4; nt++) oacc[nt] = (f32x4){0.f, 0.f, 0.f, 0.f};

    for (int t0 = 0; t0 < nk; t0 += 64) {
        int tv = t0 + lane;
        int jv = (tv == 0) ? 0 : (lo + tv - 1);
        if (jv > L_TOK - 1) jv = L_TOK - 1;
        const uint4* vp = reinterpret_cast<const uint4*>(&V[(size_t)jv * 512 + h * 64]);
        uint4 vr[8];
#pragma unroll
        for (int c = 0; c < 8; c++) vr[c] = vp[c];

        int jn[4];
#pragma unroll
        for (int nt = 0; nt < 4; nt++) {
            int t = t0 + nt * 16 + lm;
            jn[nt] = (t == 0) ? 0 : (lo + t - 1);
        }
        f32x4 sacc[4];
#pragma unroll
        for (int nt = 0; nt < 4; nt++) sacc[nt] = (f32x4){0.f, 0.f, 0.f, 0.f};
#pragma unroll
        for (int nt = 0; nt < 4; nt++) {
            int jc = jn[nt] > L_TOK - 1 ? L_TOK - 1 : jn[nt];
            const ushort_t* Kp = K + (size_t)jc * 512 + h * 64 + q4 * 8;
            bf16x8 bK0 = *reinterpret_cast<const bf16x8*>(Kp);
            bf16x8 bK1 = *reinterpret_cast<const bf16x8*>(Kp + 32);
            sacc[nt] = __builtin_amdgcn_mfma_f32_16x16x32_bf16(aQ0, bK0, sacc[nt], 0, 0, 0);
            sacc[nt] = __builtin_amdgcn_mfma_f32_16x16x32_bf16(aQ1, bK1, sacc[nt], 0, 0, 0);
        }

#pragma unroll
        for (int c = 0; c < 8; c++) {
            uint_t ww[4] = {vr[c].x, vr[c].y, vr[c].z, vr[c].w};
#pragma unroll
            for (int e = 0; e < 4; e++) {
                int d0 = c * 8 + e * 2;
                Vt[d0 * 72 + lane] = (ushort_t)(ww[e] & 0xffffu);
                Vt[(d0 + 1) * 72 + lane] = (ushort_t)(ww[e] >> 16);
            }
        }

#pragma unroll
        for (int nt = 0; nt < 4; nt++) {
            int jju = jn[nt];
#pragma unroll
            for (int r = 0; r < 4; r++) {
                float s = sacc[nt][r] * 0.125f;
                bool val = (jju == 0) || (sq[r] <= jju && jju < iq0 + r);
                sacc[nt][r] = val ? s : -INFINITY;
            }
        }

        float mnew[4], alpha[4];
#pragma unroll
        for (int r = 0; r < 4; r++) {
            float mx = fmaxf(fmaxf(sacc[0][r], sacc[1][r]), fmaxf(sacc[2][r], sacc[3][r]));
            mx = fmaxf(mx, __shfl_xor(mx, 1));
            mx = fmaxf(mx, __shfl_xor(mx, 2));
            mx = fmaxf(mx, __shfl_xor(mx, 4));
            mx = fmaxf(mx, __shfl_xor(mx, 8));
            float mn = fmaxf(m_run[r], mx);
            mnew[r] = mn;
            alpha[r] = __expf(m_run[r] - mn);
        }

#pragma unroll
        for (int r = 0; r < 4; r++) {
            float rs = 0.f;
#pragma unroll
            for (int nt = 0; nt < 4; nt++) {
                float p = __expf(sacc[nt][r] - mnew[r]);
                rs += p;
                Ps[(q4 * 4 + r) * 72 + nt * 16 + lm] = f2b(p);
            }
            rs += __shfl_xor(rs, 1);
            rs += __shfl_xor(rs, 2);
            rs += __shfl_xor(rs, 4);
            rs += __shfl_xor(rs, 8);
            l_run[r] = l_run[r] * alpha[r] + rs;
            m_run[r] = mnew[r];
        }
#pragma unroll
        for (int nt = 0; nt < 4; nt++)
#pragma unroll
            for (int r = 0; r < 4; r++) oacc[nt][r] *= alpha[r];

        bf16x8 aP0 = *reinterpret_cast<const bf16x8*>(&Ps[lm * 72 + q4 * 8]);
        bf16x8 aP1 = *reinterpret_cast<const bf16x8*>(&Ps[lm * 72 + 32 + q4 * 8]);
#pragma unroll
        for (int nt = 0; nt < 4; nt++) {
            bf16x8 bV0 = *reinterpret_cast<const bf16x8*>(&Vt[(nt * 16 + lm) * 72 + q4 * 8]);
            bf16x8 bV1 = *reinterpret_cast<const bf16x8*>(&Vt[(nt * 16 + lm) * 72 + 32 + q4 * 8]);
            oacc[nt] = __builtin_amdgcn_mfma_f32_16x16x32_bf16(aP0, bV0, oacc[nt], 0, 0, 0);
            oacc[nt] = __builtin_amdgcn_mfma_f32_16x16x32_bf16(aP1, bV1, oacc[nt], 0, 0, 0);
        }
    }

#pragma unroll
    for (int r = 0; r < 4; r++) {
        float inv = (l_run[r] > 0.f) ? (1.f / l_run[r]) : 0.f;
#pragma unroll
        for (int nt = 0; nt < 4; nt++)
            O[(size_t)(iq0 + r) * 512 + h * 64 + nt * 16 + lm] = f2b(oacc[nt][r] * inv);
    }
}

// ---------------- LayerNorm (one wave per token); RESID adds R; F32OUT selects output format
template<int RESID, int F32OUT>
__global__ __launch_bounds__(256) void ln_kernel(
    const ushort_t* __restrict__ X, const ushort_t* __restrict__ R,
    const float* __restrict__ g, const float* __restrict__ be,
    void* __restrict__ outv)
{
    int tok = blockIdx.x * 4 + (threadIdx.x >> 6);
    int lane = threadIdx.x & 63;
    size_t base = (size_t)tok * 512 + lane * 8;

    float v[8];
    {
        uint4 ux = *reinterpret_cast<const uint4*>(&X[base]);
        uint_t ua[4] = {ux.x, ux.y, ux.z, ux.w};
#pragma unroll
        for (int p = 0; p < 4; p++) {
            v[2 * p] = b2f((ushort_t)(ua[p] & 0xffffu));
            v[2 * p + 1] = b2f((ushort_t)(ua[p] >> 16));
        }
        if (RESID) {
            uint4 ur = *reinterpret_cast<const uint4*>(&R[base]);
            uint_t ub[4] = {ur.x, ur.y, ur.z, ur.w};
#pragma unroll
            for (int p = 0; p < 4; p++) {
                v[2 * p] += b2f((ushort_t)(ub[p] & 0xffffu));
                v[2 * p + 1] += b2f((ushort_t)(ub[p] >> 16));
            }
        }
    }
    float sum = 0.f;
#pragma unroll
    for (int j = 0; j < 8; j++) sum += v[j];
#pragma unroll
    for (int off = 32; off > 0; off >>= 1) sum += __shfl_xor(sum, off);
    float mu = sum * (1.f / 512.f);
    float var = 0.f;
#pragma unroll
    for (int j = 0; j < 8; j++) { float d = v[j] - mu; var += d * d; }
#pragma unroll
    for (int off = 32; off > 0; off >>= 1) var += __shfl_xor(var, off);
    float rstd = rsqrtf(var * (1.f / 512.f) + 1e-5f);

    const float4* gp = reinterpret_cast<const float4*>(g);
    const float4* bp = reinterpret_cast<const float4*>(be);
    float4 g0 = gp[2 * lane], g1 = gp[2 * lane + 1];
    float4 b0 = bp[2 * lane], b1 = bp[2 * lane + 1];
    float gg[8] = {g0.x, g0.y, g0.z, g0.w, g1.x, g1.y, g1.z, g1.w};
    float bb[8] = {b0.x, b0.y, b0.z, b0.w, b1.x, b1.y, b1.z, b1.w};

    float o[8];
#pragma unroll
    for (int j = 0; j < 8; j++) o[j] = (v[j] - mu) * rstd * gg[j] + bb[j];

    if (F32OUT) {
        float* outf = (float*)outv;
        float4 o0 = {o[0], o[1], o[2], o[3]};
        float4 o1 = {o[4], o[5], o[6], o[7]};
        *reinterpret_cast<float4*>(&outf[base]) = o0;
        *reinterpret_cast<float4*>(&outf[base + 4]) = o1;
    } else {
        ushort_t* outb = (ushort_t*)outv;
        uint_t outp[4];
#pragma unroll
        for (int p = 0; p < 4; p++)
            outp[p] = (uint_t)f2b(o[2 * p]) | ((uint_t)f2b(o[2 * p + 1]) << 16);
        uint4 ov; ov.x = outp[0]; ov.y = outp[1]; ov.z = outp[2]; ov.w = outp[3];
        *reinterpret_cast<uint4*>(&outb[base]) = ov;
    }
}

extern "C" void kernel_launch(void* const* d_in, const int* in_sizes, int n_in,
                              void* d_out, int out_size, void* d_ws, size_t ws_size,
                              hipStream_t stream) {
    const int*   idx = (const int*)d_in[0];
    const int*   seq = (const int*)d_in[1];
    const float* Wt  = (const float*)d_in[2];
    const float* bt  = (const float*)d_in[3];
    const float* Wa  = (const float*)d_in[4];
    const float* ba  = (const float*)d_in[5];
    const float* Wm  = (const float*)d_in[6];
    const float* bm  = (const float*)d_in[7];
    const float* sos = (const float*)d_in[8];
    const float* Wq  = (const float*)d_in[9];
    const float* bq  = (const float*)d_in[10];
    const float* Wk  = (const float*)d_in[11];
    const float* bk  = (const float*)d_in[12];
    const float* Wv  = (const float*)d_in[13];
    const float* bv  = (const float*)d_in[14];
    const float* Wo  = (const float*)d_in[15];
    const float* bo  = (const float*)d_in[16];
    const float* W1  = (const float*)d_in[17];
    const float* b1  = (const float*)d_in[18];
    const float* W2  = (const float*)d_in[19];
    const float* b2  = (const float*)d_in[20];
    const float* g1  = (const float*)d_in[21];
    const float* be1 = (const float*)d_in[22];
    const float* g2  = (const float*)d_in[23];
    const float* be2 = (const float*)d_in[24];

    const size_t NB = (size_t)L_TOK * DMODEL;

    int* START = (int*)d_ws;
    ushort_t* WB = (ushort_t*)d_ws + 16384;
    ushort_t* WQc = WB + 0 * WELEM;
    ushort_t* WKc = WB + 1 * WELEM;
    ushort_t* WVc = WB + 2 * WELEM;
    ushort_t* WOc = WB + 3 * WELEM;
    ushort_t* W1c = WB + 4 * WELEM;
    ushort_t* W2c = WB + 5 * WELEM;
    ushort_t* bufs = WB + 6 * WELEM;
    ushort_t* B0 = bufs;            // X / attn-out / next-layer X
    ushort_t* B1 = bufs + 1 * NB;   // Q / O-proj out / FF hidden
    ushort_t* B2 = bufs + 2 * NB;   // K / XA
    ushort_t* B3 = bufs + 3 * NB;   // V / FF2 out

    prologue_kernel<<<7681, 256, 0, stream>>>(
        Wq, Wk, Wv, Wo, W1, W2, WB,
        idx, Wt, bt, Wa, ba, Wm, bm, sos, B0,
        seq, START);

    for (int layer = 0; layer < 2; layer++) {
        gemm512<0><<<dim3(96, 8, 3), 256, 0, stream>>>(B0, WQc, WKc, WVc, bq, bk, bv, B1, B2, B3);
        attn_mfma<<<384, 256, 0, stream>>>(B1, B2, B3, START, B0);
        gemm512<0><<<dim3(96, 8, 1), 256, 0, stream>>>(B0, WOc, WOc, WOc, bo, bo, bo, B1, B1, B1);
        ln_kernel<0, 0><<<768, 256, 0, stream>>>(B1, B1, g1, be1, B2);          // XA -> B2
        gemm512<1><<<dim3(96, 8, 1), 256, 0, stream>>>(B2, W1c, W1c, W1c, b1, b1, b1, B1, B1, B1);
        gemm512<0><<<dim3(96, 8, 1), 256, 0, stream>>>(B1, W2c, W2c, W2c, b2, b2, b2, B3, B3, B3);
        if (layer == 0)
            ln_kernel<1, 0><<<768, 256, 0, stream>>>(B3, B2, g2, be2, B0);      // bf16 internal
        else
            ln_kernel<1, 1><<<768, 256, 0, stream>>>(B3, B2, g2, be2, d_out);   // fp32 final output
    }
}